// Round 8
// baseline (563.518 us; speedup 1.0000x reference)
//
#include <hip/hip_runtime.h>

typedef _Float16 f16;
typedef unsigned int uint;
typedef f16 f16x2 __attribute__((ext_vector_type(2)));
typedef f16 f16x8 __attribute__((ext_vector_type(8)));
typedef __fp16 h16x2 __attribute__((ext_vector_type(2)));
typedef float f32x4 __attribute__((ext_vector_type(4)));

#define Bn 512
#define Ln 128
#define Dn 128
#define Cn 512   // 4 gates * D

__device__ __forceinline__ float fdot2f(uint a, uint b, float c) {
#if __has_builtin(__builtin_amdgcn_fdot2)
  return __builtin_amdgcn_fdot2(__builtin_bit_cast(f16x2, a),
                                __builtin_bit_cast(f16x2, b), c, false);
#else
  f16x2 av = __builtin_bit_cast(f16x2, a), bv = __builtin_bit_cast(f16x2, b);
  return c + (float)av[0] * (float)bv[0] + (float)av[1] * (float)bv[1];
#endif
}

__device__ __forceinline__ uint pk2(float a, float b) {
#if __has_builtin(__builtin_amdgcn_cvt_pkrtz)
  h16x2 v = __builtin_amdgcn_cvt_pkrtz(a, b);
  return __builtin_bit_cast(uint, v);
#else
  f16x2 v; v[0] = (f16)a; v[1] = (f16)b;
  return __builtin_bit_cast(uint, v);
#endif
}

// DPP row_ror<N> (VALU, 2-cyc): rotational reduce within 16-lane rows.
template<int CTRL>
__device__ __forceinline__ float rorf(float x) {
#if __has_builtin(__builtin_amdgcn_mov_dpp)
  int r = __builtin_amdgcn_mov_dpp(__builtin_bit_cast(int, x), CTRL, 0xF, 0xF, true);
  return __builtin_bit_cast(float, r);
#else
  return __shfl_xor(x, (CTRL - 0x120));
#endif
}

// lane ^ 16 exchange via ds_swizzle (BitMode xor=16, and=0x1F) — LDS pipe,
// result intentionally NOT consumed at issue site (deferred to next step).
__device__ __forceinline__ int swz16i(float x) {
#if __has_builtin(__builtin_amdgcn_ds_swizzle)
  return __builtin_amdgcn_ds_swizzle(__builtin_bit_cast(int, x), 0x401F);
#else
  return __builtin_bit_cast(int, __shfl_xor(x, 16));
#endif
}

__device__ __forceinline__ void read_hu(const f16* base, uint hu[16]) {
  const uint4* hq = (const uint4*)base;
  uint4 q0 = hq[0], q1 = hq[1], q2 = hq[2], q3 = hq[3];
  hu[0]=q0.x; hu[1]=q0.y; hu[2]=q0.z; hu[3]=q0.w;
  hu[4]=q1.x; hu[5]=q1.y; hu[6]=q1.z; hu[7]=q1.w;
  hu[8]=q2.x; hu[9]=q2.y; hu[10]=q2.z; hu[11]=q2.w;
  hu[12]=q3.x; hu[13]=q3.y; hu[14]=q3.z; hu[15]=q3.w;
}

// ---------------- convert: W -> MFMA-fragment-ordered f16 (WhF), R -> transposed f16 ----------------
__global__ __launch_bounds__(256) void k_convert(const float* __restrict__ Wg,
                                                 const float* __restrict__ Rg,
                                                 f16* __restrict__ WhF,
                                                 f16* __restrict__ RT) {
  int i = blockIdx.x * 256 + threadIdx.x;
  const int nWfrag = 2 * 4 * 32 * 64;   // 16384 groups of 8 f16
  if (i < nWfrag) {
    int lane = i & 63;
    int ii   = (i >> 6) & 31;
    int kk   = (i >> 11) & 3;
    int l    = i >> 13;
    int c = ii * 16 + (lane & 15);
    int d = kk * 32 + ((lane >> 4) << 3);
    const float* src = Wg + ((size_t)(l * 512 + c) * 128 + d);
    f16* dst = WhF + (size_t)i * 8;
    #pragma unroll
    for (int j = 0; j < 8; ++j) dst[j] = (f16)src[j];
  } else {
    int j = i - nWfrag;  // 32768 = 2*4*4*32*32
    if (j < 32768) {
      int dd = j & 31;
      int e  = (j >> 5) & 31;
      int hh = (j >> 10) & 3;
      int g  = (j >> 12) & 3;
      int l  = j >> 14;
      RT[j] = (f16)Rg[((((l * 4 + g) * 4 + hh) * 32 + dd) * 32) + e];
    }
  }
}

// ---------------- GEMM chunk (device fn): 32 rows -> LDS preP buffer ----------------
// Computes 2 m-tiles (rows chunk*32 .. chunk*32+31 of this block's sequence),
// NI i7-column-groups starting at i7b, streaming B fragments from L2 (WhF is
// 256 KB, chip-hot). Gate-packed uint2 stores go to the LDS chunk buffer.
// Math identical to the r6-verified k_gemm.
template<int EMB, int NI>
__device__ void gemm_chunk(const float* __restrict__ xsrc,
                           const int* __restrict__ idr,
                           const float* __restrict__ lw,
                           const float* __restrict__ lb,
                           const f16* __restrict__ Wh,
                           const float* __restrict__ bias,
                           uint2 (*__restrict__ ldsPb)[128],
                           int chunk, int i7b) {
  int lane = threadIdx.x & 63;
  int l16 = lane & 15, quad = lane >> 4;

  float bv[NI][4];
  #pragma unroll
  for (int i = 0; i < NI; ++i)
    #pragma unroll
    for (int g = 0; g < 4; ++g)
      bv[i][g] = bias[(g * 8 + i7b + i) * 16 + l16];

  f32x4 lw4[4][2], lb4[4][2];
  #pragma unroll
  for (int kk = 0; kk < 4; ++kk)
    #pragma unroll
    for (int p = 0; p < 2; ++p) {
      int d0 = kk * 32 + quad * 8 + p * 4;
      lw4[kk][p] = *(const f32x4*)(lw + d0);
      lb4[kk][p] = *(const f32x4*)(lb + d0);
    }

  #pragma unroll 1
  for (int h = 0; h < 2; ++h) {
    int m0loc = chunk * 32 + h * 16;   // local row base within sequence
    const float* sp;
    if (EMB) sp = xsrc + (size_t)idr[m0loc + l16] * Dn + quad * 8;
    else     sp = xsrc + (size_t)(m0loc + l16) * Dn + quad * 8;

    f32x4 v[4][2];
    #pragma unroll
    for (int kk = 0; kk < 4; ++kk) {
      v[kk][0] = *(const f32x4*)(sp + kk * 32);
      v[kk][1] = *(const f32x4*)(sp + kk * 32 + 4);
    }
    float s1 = 0.f, s2 = 0.f;
    #pragma unroll
    for (int kk = 0; kk < 4; ++kk)
      #pragma unroll
      for (int p = 0; p < 2; ++p)
        #pragma unroll
        for (int j = 0; j < 4; ++j) {
          float vv = v[kk][p][j];
          s1 += vv; s2 = fmaf(vv, vv, s2);
        }
    s1 += __shfl_xor(s1, 16);  s2 += __shfl_xor(s2, 16);
    s1 += __shfl_xor(s1, 32);  s2 += __shfl_xor(s2, 32);
    float mu = s1 * (1.f / 128.f);
    float var = s2 * (1.f / 128.f) - mu * mu;
    float rs = rsqrtf(var + 1e-5f);

    f16x8 a[4];
    #pragma unroll
    for (int kk = 0; kk < 4; ++kk)
      #pragma unroll
      for (int p = 0; p < 2; ++p)
        #pragma unroll
        for (int j = 0; j < 4; ++j)
          a[kk][p * 4 + j] = (f16)((v[kk][p][j] - mu) * rs * lw4[kk][p][j] + lb4[kk][p][j]);

    f32x4 acc[NI][4] = {};
    #pragma unroll
    for (int kk = 0; kk < 4; ++kk)
      #pragma unroll
      for (int i = 0; i < NI; ++i)
        #pragma unroll
        for (int g = 0; g < 4; ++g) {
          f16x8 bf = *(const f16x8*)(Wh + (size_t)(kk * 32 + g * 8 + i7b + i) * 512 + lane * 8);
          acc[i][g] = __builtin_amdgcn_mfma_f32_16x16x32_f16(a[kk], bf, acc[i][g], 0, 0, 0);
        }

    #pragma unroll
    for (int r = 0; r < 4; ++r) {
      int rowl = h * 16 + quad * 4 + r;   // 0..31 within chunk
      #pragma unroll
      for (int i = 0; i < NI; ++i) {
        uint2 vv;
        vv.x = pk2(acc[i][0][r] + bv[i][0], acc[i][1][r] + bv[i][1]);
        vv.y = pk2(acc[i][2][r] + bv[i][2], acc[i][3][r] + bv[i][3]);
        ldsPb[rowl][(i7b + i) * 16 + l16] = vv;
      }
    }
  }
}

// ---------------- fused per-sequence kernel: GEMM chunks (waves 2,3) feed the
// scan (waves 0,1) through double-buffered LDS; preP never touches global.
// Round c: waves 0,1 scan chunk c from ldsP[c&1]; waves 2,3 produce chunk c+1
// into ldsP[(c+1)&1]; uniform __syncthreads per round. Scan/GEMM math verbatim
// from the verified r4/r6 kernels.
template<int LAST>
__global__ __launch_bounds__(256, 2) void k_fused(const int* __restrict__ ids,
                                                  const float* __restrict__ emb,
                                                  const float* __restrict__ ln_w,
                                                  const float* __restrict__ ln_b,
                                                  const float* __restrict__ bg,
                                                  const float* __restrict__ gn_w,
                                                  const float* __restrict__ hw1,
                                                  const float* __restrict__ hb1,
                                                  const float* __restrict__ hw2,
                                                  const float* __restrict__ hb2,
                                                  const f16* __restrict__ WhF,
                                                  const f16* __restrict__ RT,
                                                  float* __restrict__ x1,
                                                  float* __restrict__ out) {
  const int w = threadIdx.x >> 6;       // wave 0..3
  const int lane = threadIdx.x & 63;
  const int b = blockIdx.x;             // sequence

  __shared__ __align__(16) uint2 ldsP[2][32][128];   // 64 KB double buffer
  __shared__ __align__(16) f16 hsh[2][64];
  __shared__ float pool[128];
  __shared__ float hid[64];

  const float* lw   = ln_w + (LAST ? Dn : 0);
  const float* lb   = ln_b + (LAST ? Dn : 0);
  const float* bias = bg + (LAST ? Cn : 0);
  const f16*   Wh   = WhF + (LAST ? 65536 : 0);
  const f16*   RTl  = RT + (LAST ? 16384 : 0);
  const float* gnw  = gn_w + (LAST ? Dn : 0);
  const float* gsrc = LAST ? (x1 + (size_t)b * Ln * Dn) : emb;
  const int*   idr  = ids + b * Ln;

  // prologue: chunk 0 produced by all 4 waves (i7 = {2w, 2w+1})
  gemm_chunk<LAST ? 0 : 1, 2>(gsrc, idr, lw, lb, Wh, bias, ldsP[0], 0, 2 * w);
  __syncthreads();

  // ---- scan state (waves 0,1 only; d = w*64 + lane covers 0..127) ----
  const int d = (w << 6) + lane;
  const int head = d >> 5;
  const int e = d & 31;
  const int half = lane >> 5;
  float gw = 0.f;
  const f16* hbase = &hsh[w & 1][half * 32];
  const float* xp = x1 + (size_t)b * Ln * Dn + d;   // LAST residual source
  float* xo = x1 + (size_t)b * Ln * Dn + d;         // LAST=0 output rows
  float xb[4]; int idb[4];
  float cc = 0.f, nc = 0.f, mc = 0.f, psum = 0.f;
  float hprev = 0.f, xprev = 0.f;
  float u1 = 0.f, u2 = 0.f;
  int   w1 = 0,   w2 = 0;

  if (w < 2) {
    gw = gnw[d];
    hsh[w][lane] = (f16)0.f;   // wave-local, DS in-order
    #pragma unroll
    for (int k = 0; k < 4; ++k) {
      if (LAST) { xb[k] = xp[(size_t)k * Dn]; idb[k] = 0; }
      else      { xb[k] = emb[(size_t)idr[k] * Dn + d]; idb[k] = idr[k + 4]; }
    }
  }

  #pragma unroll 1
  for (int c = 0; c < 4; ++c) {
    if (w < 2) {
      // reload rr + hu each round (keeps them dead in the gemm branch -> no
      // register-liveness union across the divergent paths)
      uint rr[4][16];
      const uint* RT32 = (const uint*)RTl;
      #pragma unroll
      for (int g = 0; g < 4; ++g) {
        const uint* p = RT32 + ((g * 4 + head) * 32 + e) * 16;
        #pragma unroll
        for (int j = 0; j < 16; ++j) rr[g][j] = p[j];
      }
      uint hu[16];
      read_hu(hbase, hu);
      const uint2* Pc = &ldsP[c & 1][0][0];
      uint2 pcn = Pc[d];   // local step 0 of this chunk

      #pragma unroll 1
      for (int t8 = 0; t8 < 8; ++t8) {
        #pragma unroll
        for (int k = 0; k < 4; ++k) {
          int s = t8 * 4 + k;
          int tt = c * 32 + s;
          uint2 pc = pcn;
          if (s < 31) pcn = Pc[(s + 1) * 128 + d];
          float xc = xb[k];
          if (LAST) {
            xb[k] = xp[(size_t)(tt + 4) * Dn];
          } else {
            xb[k] = emb[(size_t)idb[k] * Dn + d];
            int ni = tt + 8;
            idb[k] = idr[ni > 127 ? 127 : ni];
          }

          // deferred GN of step tt-1 (swizzle halves combined here)
          if (tt > 0) {
            float s1 = u1 + __builtin_bit_cast(float, w1);
            float s2 = u2 + __builtin_bit_cast(float, w2);
            float mu = s1 * (1.f / 32.f);
            float va = s2 * (1.f / 32.f) - mu * mu;
            float ov = xprev + (hprev - mu) * rsqrtf(va + 1e-5f) * gw;
            if (LAST) psum += ov;
            else      xo[(size_t)(tt - 1) * Dn] = ov;
          }

          // recurrence dot products: 8 chains of 8
          float a0 = 0.f, a1 = 0.f, a2 = 0.f, a3 = 0.f;
          float c0 = 0.f, c1 = 0.f, c2 = 0.f, c3 = 0.f;
          #pragma unroll
          for (int j = 0; j < 8; ++j) {
            a0 = fdot2f(hu[j], rr[0][j], a0);
            a1 = fdot2f(hu[j], rr[1][j], a1);
            a2 = fdot2f(hu[j], rr[2][j], a2);
            a3 = fdot2f(hu[j], rr[3][j], a3);
            c0 = fdot2f(hu[j + 8], rr[0][j + 8], c0);
            c1 = fdot2f(hu[j + 8], rr[1][j + 8], c1);
            c2 = fdot2f(hu[j + 8], rr[2][j + 8], c2);
            c3 = fdot2f(hu[j + 8], rr[3][j + 8], c3);
          }
          f16x2 lo = __builtin_bit_cast(f16x2, pc.x);
          f16x2 hi = __builtin_bit_cast(f16x2, pc.y);
          float it = ((float)lo[0] + a0) + c0;
          float ft = ((float)lo[1] + a1) + c1;
          float zt = ((float)hi[0] + a2) + c2;
          float ot = ((float)hi[1] + a3) + c3;

          float mn = fmaxf(ft + mc, it);
          float iv = __expf(it - mn);
          float fv = __expf(ft + mc - mn);
          float zc = fminf(fmaxf(zt, -15.f), 15.f);
          float ez = __expf(2.f * zc);
          float tz = (ez - 1.f) * __builtin_amdgcn_rcpf(ez + 1.f);
          float cn = fv * cc + iv * tz;
          float nn = fv * nc + iv;
          float hn = cn * __builtin_amdgcn_rcpf((1.f + __expf(-ot)) * nn);
          cc = cn; nc = nn; mc = mn;

          hsh[w][lane] = (f16)hn;                       // h exchange

          float t1v = hn, t2v = hn * hn;
          t1v += rorf<0x121>(t1v);  t2v += rorf<0x121>(t2v);
          t1v += rorf<0x122>(t1v);  t2v += rorf<0x122>(t2v);
          t1v += rorf<0x124>(t1v);  t2v += rorf<0x124>(t2v);
          t1v += rorf<0x128>(t1v);  t2v += rorf<0x128>(t2v);
          w1 = swz16i(t1v);
          w2 = swz16i(t2v);
          u1 = t1v; u2 = t2v;

          read_hu(hbase, hu);                           // hu for t+1

          hprev = hn; xprev = xc;
        }
      }
    } else if (c < 3) {
      // produce chunk c+1 into the other buffer (waves 2,3; i7 split 0-3 / 4-7)
      gemm_chunk<LAST ? 0 : 1, 4>(gsrc, idr, lw, lb, Wh, bias,
                                  ldsP[(c + 1) & 1], c + 1, (w - 2) * 4);
    }
    __syncthreads();
  }

  // epilogue: GN of step 127
  if (w < 2) {
    float s1 = u1 + __builtin_bit_cast(float, w1);
    float s2 = u2 + __builtin_bit_cast(float, w2);
    float mu = s1 * (1.f / 32.f);
    float va = s2 * (1.f / 32.f) - mu * mu;
    float ov = xprev + (hprev - mu) * rsqrtf(va + 1e-5f) * gw;
    if (LAST) { psum += ov; pool[d] = psum * (1.f / 128.f); }
    else      xo[(size_t)(Ln - 1) * Dn] = ov;
  }
  if (LAST) {
    __syncthreads();
    if (w == 0) {
      float acc = hb1[lane];
      const float* wr = hw1 + (size_t)lane * Dn;
      #pragma unroll 8
      for (int dd = 0; dd < Dn; dd += 4) {
        f32x4 wv = *(const f32x4*)(wr + dd);
        acc += wv[0]*pool[dd] + wv[1]*pool[dd+1] + wv[2]*pool[dd+2] + wv[3]*pool[dd+3];
      }
      hid[lane] = fmaxf(acc, 0.f);
    }
    __syncthreads();
    if (w == 0 && lane < 2) {
      float acc = hb2[lane];
      const float* wr = hw2 + lane * 64;
      #pragma unroll 4
      for (int j = 0; j < 64; ++j) acc += hid[j] * wr[j];
      out[b * 2 + lane] = acc;
    }
  }
}

extern "C" void kernel_launch(void* const* d_in, const int* in_sizes, int n_in,
                              void* d_out, int out_size, void* d_ws, size_t ws_size,
                              hipStream_t stream) {
  const int*   ids  = (const int*)d_in[0];
  const float* emb  = (const float*)d_in[1];
  const float* ln_w = (const float*)d_in[2];
  const float* ln_b = (const float*)d_in[3];
  const float* Wg   = (const float*)d_in[4];
  const float* Rg   = (const float*)d_in[5];
  const float* bg   = (const float*)d_in[6];
  const float* gn_w = (const float*)d_in[7];
  const float* w1   = (const float*)d_in[8];
  const float* b1   = (const float*)d_in[9];
  const float* w2   = (const float*)d_in[10];
  const float* b2   = (const float*)d_in[11];
  float* out = (float*)d_out;

  char* ws = (char*)d_ws;
  float* x1  = (float*)ws;                         // 33,554,432 B
  f16*   WhF = (f16*)(ws + 33554432);              //    262,144 B
  f16*   RT  = (f16*)(ws + 33554432 + 262144);     //     65,536 B

  k_convert<<<192, 256, 0, stream>>>(Wg, Rg, WhF, RT);

  // layer 0: fused GEMM->LDS->scan (writes x1)
  k_fused<0><<<512, 256, 0, stream>>>(ids, emb, ln_w, ln_b, bg, gn_w,
                                      w1, b1, w2, b2, WhF, RT, x1, out);
  // layer 1: fused GEMM->LDS->scan + pooling + head
  k_fused<1><<<512, 256, 0, stream>>>(ids, emb, ln_w, ln_b, bg, gn_w,
                                      w1, b1, w2, b2, WhF, RT, x1, out);
}

// Round 9
// 315.520 us; speedup vs baseline: 1.7860x; 1.7860x over previous
//
#include <hip/hip_runtime.h>

typedef _Float16 f16;
typedef unsigned int uint;
typedef f16 f16x2 __attribute__((ext_vector_type(2)));
typedef f16 f16x8 __attribute__((ext_vector_type(8)));
typedef __fp16 h16x2 __attribute__((ext_vector_type(2)));
typedef float f32x4 __attribute__((ext_vector_type(4)));

#define Bn 512
#define Ln 128
#define Dn 128
#define Cn 512   // 4 gates * D

__device__ __forceinline__ float fdot2f(uint a, uint b, float c) {
#if __has_builtin(__builtin_amdgcn_fdot2)
  return __builtin_amdgcn_fdot2(__builtin_bit_cast(f16x2, a),
                                __builtin_bit_cast(f16x2, b), c, false);
#else
  f16x2 av = __builtin_bit_cast(f16x2, a), bv = __builtin_bit_cast(f16x2, b);
  return c + (float)av[0] * (float)bv[0] + (float)av[1] * (float)bv[1];
#endif
}

__device__ __forceinline__ uint pk2(float a, float b) {
#if __has_builtin(__builtin_amdgcn_cvt_pkrtz)
  h16x2 v = __builtin_amdgcn_cvt_pkrtz(a, b);
  return __builtin_bit_cast(uint, v);
#else
  f16x2 v; v[0] = (f16)a; v[1] = (f16)b;
  return __builtin_bit_cast(uint, v);
#endif
}

// DPP row_ror<N> (VALU, 2-cyc): rotational reduce within 16-lane rows.
template<int CTRL>
__device__ __forceinline__ float rorf(float x) {
#if __has_builtin(__builtin_amdgcn_mov_dpp)
  int r = __builtin_amdgcn_mov_dpp(__builtin_bit_cast(int, x), CTRL, 0xF, 0xF, true);
  return __builtin_bit_cast(float, r);
#else
  return __shfl_xor(x, (CTRL - 0x120));
#endif
}

// lane ^ 16 exchange via ds_swizzle (BitMode xor=16, and=0x1F) — LDS pipe,
// result intentionally NOT consumed at issue site (deferred to next step).
__device__ __forceinline__ int swz16i(float x) {
#if __has_builtin(__builtin_amdgcn_ds_swizzle)
  return __builtin_amdgcn_ds_swizzle(__builtin_bit_cast(int, x), 0x401F);
#else
  return __builtin_bit_cast(int, __shfl_xor(x, 16));
#endif
}

__device__ __forceinline__ void read_hu(const f16* base, uint hu[16]) {
  const uint4* hq = (const uint4*)base;
  uint4 q0 = hq[0], q1 = hq[1], q2 = hq[2], q3 = hq[3];
  hu[0]=q0.x; hu[1]=q0.y; hu[2]=q0.z; hu[3]=q0.w;
  hu[4]=q1.x; hu[5]=q1.y; hu[6]=q1.z; hu[7]=q1.w;
  hu[8]=q2.x; hu[9]=q2.y; hu[10]=q2.z; hu[11]=q2.w;
  hu[12]=q3.x; hu[13]=q3.y; hu[14]=q3.z; hu[15]=q3.w;
}

// ---------------- convert: W -> MFMA-fragment-ordered f16 (WhF), R -> transposed f16 ----------------
__global__ __launch_bounds__(256) void k_convert(const float* __restrict__ Wg,
                                                 const float* __restrict__ Rg,
                                                 f16* __restrict__ WhF,
                                                 f16* __restrict__ RT) {
  int i = blockIdx.x * 256 + threadIdx.x;
  const int nWfrag = 2 * 4 * 32 * 64;   // 16384 groups of 8 f16
  if (i < nWfrag) {
    int lane = i & 63;
    int ii   = (i >> 6) & 31;
    int kk   = (i >> 11) & 3;
    int l    = i >> 13;
    int c = ii * 16 + (lane & 15);
    int d = kk * 32 + ((lane >> 4) << 3);
    const float* src = Wg + ((size_t)(l * 512 + c) * 128 + d);
    f16* dst = WhF + (size_t)i * 8;
    #pragma unroll
    for (int j = 0; j < 8; ++j) dst[j] = (f16)src[j];
  } else {
    int j = i - nWfrag;  // 32768 = 2*4*4*32*32
    if (j < 32768) {
      int dd = j & 31;
      int e  = (j >> 5) & 31;
      int hh = (j >> 10) & 3;
      int g  = (j >> 12) & 3;
      int l  = j >> 14;
      RT[j] = (f16)Rg[((((l * 4 + g) * 4 + hh) * 32 + dd) * 32) + e];
    }
  }
}

// ---------------- GEMM, B-resident-in-registers, inline LN, 2-stage A pipeline ----------------
// Wave w owns output cols i in {2w,2w+1}+{0,8,16,24}; its 32 B-fragments
// (128 VGPR) load once per block. NEW vs r6: tile t+1's A-row loads (and its
// ids value, one stage earlier still) are issued BEFORE computing tile t, so
// the random-row gather latency hides under the previous tile's LN+MFMA+stores.
template<int EMB>
__global__ __launch_bounds__(256, 2) void k_gemm(const float* __restrict__ xsrc,
                                                 const int* __restrict__ ids,
                                                 const float* __restrict__ lw,
                                                 const float* __restrict__ lb,
                                                 const f16* __restrict__ WhF,
                                                 const float* __restrict__ bias,
                                                 uint2* __restrict__ preP) {
  int w = threadIdx.x >> 6;
  int lane = threadIdx.x & 63;
  int l16 = lane & 15, quad = lane >> 4;
  int m_base = blockIdx.x * 128;

  // resident B fragments: [j][g][kk], i = 2w + j + 8g
  f16x8 bregs[2][4][4];
  #pragma unroll
  for (int j = 0; j < 2; ++j)
    #pragma unroll
    for (int g = 0; g < 4; ++g) {
      int i = 2 * w + j + 8 * g;
      #pragma unroll
      for (int kk = 0; kk < 4; ++kk)
        bregs[j][g][kk] = *(const f16x8*)(WhF + (size_t)(kk * 32 + i) * 512 + lane * 8);
    }
  float bv[2][4];
  #pragma unroll
  for (int j = 0; j < 2; ++j)
    #pragma unroll
    for (int g = 0; g < 4; ++g)
      bv[j][g] = bias[(2 * w + j + 8 * g) * 16 + l16];

  // pipeline prologue: tile 0 A-rows + tile-1 id
  int idn = 0;
  const float* sp0;
  if (EMB) {
    int id0 = ids[m_base + l16];
    idn = ids[m_base + 16 + l16];
    sp0 = xsrc + (size_t)id0 * Dn + quad * 8;
  } else {
    sp0 = xsrc + (size_t)(m_base + l16) * Dn + quad * 8;
  }
  f32x4 v[4][2], vn[4][2];
  #pragma unroll
  for (int kk = 0; kk < 4; ++kk) {
    v[kk][0] = *(const f32x4*)(sp0 + kk * 32);
    v[kk][1] = *(const f32x4*)(sp0 + kk * 32 + 4);
  }

  #pragma unroll 1
  for (int t16 = 0; t16 < 8; ++t16) {
    int m0 = m_base + t16 * 16;

    // issue next tile's A loads first (latency hides under this tile's work)
    if (t16 < 7) {
      const float* spn;
      if (EMB) spn = xsrc + (size_t)idn * Dn + quad * 8;
      else     spn = xsrc + (size_t)(m0 + 16 + l16) * Dn + quad * 8;
      #pragma unroll
      for (int kk = 0; kk < 4; ++kk) {
        vn[kk][0] = *(const f32x4*)(spn + kk * 32);
        vn[kk][1] = *(const f32x4*)(spn + kk * 32 + 4);
      }
      if (EMB && t16 < 6) idn = ids[m_base + (t16 + 2) * 16 + l16];
    }

    // LN stats on current tile
    float s1 = 0.f, s2 = 0.f;
    #pragma unroll
    for (int kk = 0; kk < 4; ++kk)
      #pragma unroll
      for (int p = 0; p < 2; ++p)
        #pragma unroll
        for (int j = 0; j < 4; ++j) {
          float vv = v[kk][p][j];
          s1 += vv; s2 = fmaf(vv, vv, s2);
        }
    s1 += __shfl_xor(s1, 16);  s2 += __shfl_xor(s2, 16);
    s1 += __shfl_xor(s1, 32);  s2 += __shfl_xor(s2, 32);
    float mu = s1 * (1.f / 128.f);
    float var = s2 * (1.f / 128.f) - mu * mu;
    float rs = rsqrtf(var + 1e-5f);

    // normalize -> f16 fragments (lw/lb reloaded per tile: L1-hot, saves VGPRs)
    f16x8 a[4];
    #pragma unroll
    for (int kk = 0; kk < 4; ++kk)
      #pragma unroll
      for (int p = 0; p < 2; ++p) {
        int d0 = kk * 32 + quad * 8 + p * 4;
        f32x4 lw4 = *(const f32x4*)(lw + d0);
        f32x4 lb4 = *(const f32x4*)(lb + d0);
        #pragma unroll
        for (int j = 0; j < 4; ++j)
          a[kk][p * 4 + j] = (f16)((v[kk][p][j] - mu) * rs * lw4[j] + lb4[j]);
      }

    f32x4 acc[2][4] = {};
    #pragma unroll
    for (int kk = 0; kk < 4; ++kk)
      #pragma unroll
      for (int j = 0; j < 2; ++j)
        #pragma unroll
        for (int g = 0; g < 4; ++g)
          acc[j][g] = __builtin_amdgcn_mfma_f32_16x16x32_f16(a[kk], bregs[j][g][kk], acc[j][g], 0, 0, 0);

    #pragma unroll
    for (int r = 0; r < 4; ++r) {
      int m = m0 + quad * 4 + r;
      #pragma unroll
      for (int j = 0; j < 2; ++j) {
        uint2 vv;
        vv.x = pk2(acc[j][0][r] + bv[j][0], acc[j][1][r] + bv[j][1]);
        vv.y = pk2(acc[j][2][r] + bv[j][2], acc[j][3][r] + bv[j][3]);
        preP[(size_t)m * Dn + (2 * w + j) * 16 + l16] = vv;
      }
    }

    // rotate pipeline
    if (t16 < 7) {
      #pragma unroll
      for (int kk = 0; kk < 4; ++kk) { v[kk][0] = vn[kk][0]; v[kk][1] = vn[kk][1]; }
    }
  }
}

// ---------------- fused scan (r4 pipelined schedule, unchanged math) ----------------
// LAST=0 (layer 0): residual x gathered directly from emb[ids[t]] per step;
//                   writes xout = x1.
// LAST=1 (layer 1): residual from x1; mean-pool accumulated in-register; head
//                   MLP (128->64 relu ->2) computed in the epilogue via LDS.
template<int LAST>
__global__ __launch_bounds__(256, 1) void k_scan(const uint2* __restrict__ preP,
                                                 const f16* __restrict__ RT,
                                                 const float* __restrict__ gnw,
                                                 const float* __restrict__ xsrc,
                                                 const int* __restrict__ ids,
                                                 float* __restrict__ xout,
                                                 const float* __restrict__ hw1,
                                                 const float* __restrict__ hb1,
                                                 const float* __restrict__ hw2,
                                                 const float* __restrict__ hb2,
                                                 float* __restrict__ out) {
  const int w = threadIdx.x >> 6;       // wave 0..3
  const int lane = threadIdx.x & 63;
  const int s = w >> 1;                 // seq within block
  const int b = blockIdx.x * 2 + s;
  const int d = ((w & 1) << 6) + lane;  // element 0..127 of this seq
  const int head = d >> 5;
  const int e = d & 31;
  const int half = lane >> 5;

  __shared__ __align__(16) f16 hsh[4][64];   // per-wave h exchange
  __shared__ float pool2[2][128];            // LAST: pooled rows
  __shared__ float hid2[2][64];              // LAST: hidden layer

  uint rr[4][16];
  const uint* RT32 = (const uint*)RT;
  #pragma unroll
  for (int g = 0; g < 4; ++g) {
    const uint* p = RT32 + ((g * 4 + head) * 32 + e) * 16;
    #pragma unroll
    for (int j = 0; j < 16; ++j) rr[g][j] = p[j];
  }
  const float gw = gnw[d];
  const f16* hbase = &hsh[w][half * 32];   // my head-group's 32 h values

  hsh[w][lane] = (f16)0.f;   // wave-local, DS in-order

  const uint2* pp = preP + (size_t)b * Ln * Dn + d;   // + t*Dn
  const float* xp = xsrc + (size_t)b * Ln * Dn + d;   // LAST=1 residual path
  const int*   idr = ids + b * Ln;                    // LAST=0 gather path
  float* xo = xout + (size_t)b * Ln * Dn + d;

  // 4-deep prefetch pipeline (preP overrun stays inside workspace)
  uint2 pb[4]; float xb[4]; int idb[4];
  #pragma unroll
  for (int k = 0; k < 4; ++k) {
    pb[k] = pp[(size_t)k * Dn];
    if (LAST) {
      xb[k] = xp[(size_t)k * Dn];
    } else {
      xb[k] = xsrc[(size_t)idr[k] * Dn + d];
      idb[k] = idr[k + 4];
    }
  }

  // preheader: hu for t=0 (all zeros, but read keeps the pipeline uniform)
  uint hu[16];
  read_hu(hbase, hu);

  float cc = 0.f, nc = 0.f, mc = 0.f, psum = 0.f;
  float hprev = 0.f, xprev = 0.f;
  float u1 = 0.f, u2 = 0.f;   // 16-row partial GN sums of step t-1
  int   w1 = 0,   w2 = 0;     // raw ds_swizzle results (other 16-row sums)

  #pragma unroll 1
  for (int t = 0; t < Ln; t += 4) {
    #pragma unroll
    for (int k = 0; k < 4; ++k) {
      int tt = t + k;
      uint2 pc = pb[k]; float xc = xb[k];
      pb[k] = pp[(size_t)(tt + 4) * Dn];
      if (LAST) {
        xb[k] = xp[(size_t)(tt + 4) * Dn];
      } else {
        xb[k] = xsrc[(size_t)idb[k] * Dn + d];
        int ni = tt + 8;
        idb[k] = idr[ni > 127 ? 127 : ni];
      }

      // GN of step tt-1: combine deferred swizzle halves here
      if (tt > 0) {
        float s1 = u1 + __builtin_bit_cast(float, w1);
        float s2 = u2 + __builtin_bit_cast(float, w2);
        float mu = s1 * (1.f / 32.f);
        float va = s2 * (1.f / 32.f) - mu * mu;
        float ov = xprev + (hprev - mu) * rsqrtf(va + 1e-5f) * gw;
        if (LAST) psum += ov;
        else      xo[(size_t)(tt - 1) * Dn] = ov;
      }

      // recurrence dot products: 8 chains of 8 (2-way split per gate)
      float a0 = 0.f, a1 = 0.f, a2 = 0.f, a3 = 0.f;
      float c0 = 0.f, c1 = 0.f, c2 = 0.f, c3 = 0.f;
      #pragma unroll
      for (int j = 0; j < 8; ++j) {
        a0 = fdot2f(hu[j], rr[0][j], a0);
        a1 = fdot2f(hu[j], rr[1][j], a1);
        a2 = fdot2f(hu[j], rr[2][j], a2);
        a3 = fdot2f(hu[j], rr[3][j], a3);
        c0 = fdot2f(hu[j + 8], rr[0][j + 8], c0);
        c1 = fdot2f(hu[j + 8], rr[1][j + 8], c1);
        c2 = fdot2f(hu[j + 8], rr[2][j + 8], c2);
        c3 = fdot2f(hu[j + 8], rr[3][j + 8], c3);
      }
      f16x2 lo = __builtin_bit_cast(f16x2, pc.x);
      f16x2 hi = __builtin_bit_cast(f16x2, pc.y);
      float it = ((float)lo[0] + a0) + c0;
      float ft = ((float)lo[1] + a1) + c1;
      float zt = ((float)hi[0] + a2) + c2;
      float ot = ((float)hi[1] + a3) + c3;

      float mn = fmaxf(ft + mc, it);
      float iv = __expf(it - mn);
      float fv = __expf(ft + mc - mn);
      float zc = fminf(fmaxf(zt, -15.f), 15.f);
      float ez = __expf(2.f * zc);
      float tz = (ez - 1.f) * __builtin_amdgcn_rcpf(ez + 1.f);
      float cn = fv * cc + iv * tz;
      float nn = fv * nc + iv;
      // h = sigmoid(ot) * c / n = c / ((1 + exp(-ot)) * n)  — single rcp
      float hn = cn * __builtin_amdgcn_rcpf((1.f + __expf(-ot)) * nn);
      cc = cn; nc = nn; mc = mn;

      // --- DS schedule for next step (issue-only, no consumption here) ---
      hsh[w][lane] = (f16)hn;                       // DS op 1: h exchange

      float t1v = hn, t2v = hn * hn;                // VALU rors: 16-row sums
      t1v += rorf<0x121>(t1v);  t2v += rorf<0x121>(t2v);   // ror 1
      t1v += rorf<0x122>(t1v);  t2v += rorf<0x122>(t2v);   // ror 2
      t1v += rorf<0x124>(t1v);  t2v += rorf<0x124>(t2v);   // ror 4
      t1v += rorf<0x128>(t1v);  t2v += rorf<0x128>(t2v);   // ror 8
      w1 = swz16i(t1v);                             // DS ops 2,3: xor-16
      w2 = swz16i(t2v);                             //   (combined next step)
      u1 = t1v; u2 = t2v;

      read_hu(hbase, hu);                           // DS ops 4..7: hu for t+1

      hprev = hn; xprev = xc;
    }
  }

  // epilogue: groupnorm of step 127
  {
    float s1 = u1 + __builtin_bit_cast(float, w1);
    float s2 = u2 + __builtin_bit_cast(float, w2);
    float mu = s1 * (1.f / 32.f);
    float va = s2 * (1.f / 32.f) - mu * mu;
    float ov = xprev + (hprev - mu) * rsqrtf(va + 1e-5f) * gw;
    if (LAST) {
      psum += ov;
      pool2[s][d] = psum * (1.f / 128.f);
      __syncthreads();
      // head MLP: waves 0,2 handle local seqs 0,1
      if ((w & 1) == 0) {
        int sq = w >> 1;
        float acc = hb1[lane];
        const float* wr = hw1 + (size_t)lane * Dn;
        const float* pl = &pool2[sq][0];
        #pragma unroll 8
        for (int dd = 0; dd < Dn; dd += 4) {
          f32x4 wv = *(const f32x4*)(wr + dd);
          acc += wv[0]*pl[dd] + wv[1]*pl[dd+1] + wv[2]*pl[dd+2] + wv[3]*pl[dd+3];
        }
        hid2[sq][lane] = fmaxf(acc, 0.f);
      }
      __syncthreads();
      if ((w & 1) == 0 && lane < 2) {
        int sq = w >> 1;
        float acc = hb2[lane];
        const float* wr = hw2 + lane * 64;
        #pragma unroll 4
        for (int j = 0; j < 64; ++j) acc += hid2[sq][j] * wr[j];
        out[(blockIdx.x * 2 + sq) * 2 + lane] = acc;
      }
    } else {
      xo[(size_t)(Ln - 1) * Dn] = ov;
    }
  }
}

extern "C" void kernel_launch(void* const* d_in, const int* in_sizes, int n_in,
                              void* d_out, int out_size, void* d_ws, size_t ws_size,
                              hipStream_t stream) {
  const int*   ids  = (const int*)d_in[0];
  const float* emb  = (const float*)d_in[1];
  const float* ln_w = (const float*)d_in[2];
  const float* ln_b = (const float*)d_in[3];
  const float* Wg   = (const float*)d_in[4];
  const float* Rg   = (const float*)d_in[5];
  const float* bg   = (const float*)d_in[6];
  const float* gn_w = (const float*)d_in[7];
  const float* w1   = (const float*)d_in[8];
  const float* b1   = (const float*)d_in[9];
  const float* w2   = (const float*)d_in[10];
  const float* b2   = (const float*)d_in[11];
  float* out = (float*)d_out;

  char* ws = (char*)d_ws;
  uint2* preP = (uint2*)ws;                        // 67,108,864 B
  float* x1   = (float*)(ws + 67108864);           // 33,554,432 B
  f16*   WhF  = (f16*)(ws + 100663296);            //    262,144 B
  f16*   RT   = (f16*)(ws + 100663296 + 262144);   //     65,536 B

  k_convert<<<192, 256, 0, stream>>>(Wg, Rg, WhF, RT);

  // layer 0: gather+LN fused into GEMM; scan gathers residual from emb directly
  k_gemm<1><<<512, 256, 0, stream>>>(emb, ids, ln_w, ln_b, WhF, bg, preP);
  k_scan<0><<<256, 256, 0, stream>>>(preP, RT, gn_w, emb, ids, x1,
                                     nullptr, nullptr, nullptr, nullptr, nullptr);
  // layer 1: LN fused into GEMM; head MLP fused into scan epilogue
  k_gemm<0><<<512, 256, 0, stream>>>(x1, nullptr, ln_w + Dn, ln_b + Dn,
                                     WhF + 65536, bg + Cn, preP);
  k_scan<1><<<256, 256, 0, stream>>>(preP, RT + 16384, gn_w + Dn, x1, nullptr,
                                     nullptr, w1, b1, w2, b2, out);
}

// Round 12
// 259.228 us; speedup vs baseline: 2.1738x; 1.2172x over previous
//
#include <hip/hip_runtime.h>

typedef _Float16 f16;
typedef unsigned int uint;
typedef f16 f16x2 __attribute__((ext_vector_type(2)));
typedef f16 f16x8 __attribute__((ext_vector_type(8)));
typedef __fp16 h16x2 __attribute__((ext_vector_type(2)));
typedef float f32x4 __attribute__((ext_vector_type(4)));

#define Bn 512
#define Ln 128
#define Dn 128
#define Cn 512   // 4 gates * D

__device__ __forceinline__ float fdot2f(uint a, uint b, float c) {
#if __has_builtin(__builtin_amdgcn_fdot2)
  return __builtin_amdgcn_fdot2(__builtin_bit_cast(f16x2, a),
                                __builtin_bit_cast(f16x2, b), c, false);
#else
  f16x2 av = __builtin_bit_cast(f16x2, a), bv = __builtin_bit_cast(f16x2, b);
  return c + (float)av[0] * (float)bv[0] + (float)av[1] * (float)bv[1];
#endif
}

__device__ __forceinline__ uint pk2(float a, float b) {
#if __has_builtin(__builtin_amdgcn_cvt_pkrtz)
  h16x2 v = __builtin_amdgcn_cvt_pkrtz(a, b);
  return __builtin_bit_cast(uint, v);
#else
  f16x2 v; v[0] = (f16)a; v[1] = (f16)b;
  return __builtin_bit_cast(uint, v);
#endif
}

// DPP row_ror<N> (VALU, 2-cyc): rotational reduce within 16-lane rows.
template<int CTRL>
__device__ __forceinline__ float rorf(float x) {
#if __has_builtin(__builtin_amdgcn_mov_dpp)
  int r = __builtin_amdgcn_mov_dpp(__builtin_bit_cast(int, x), CTRL, 0xF, 0xF, true);
  return __builtin_bit_cast(float, r);
#else
  return __shfl_xor(x, (CTRL - 0x120));
#endif
}

// lane ^ 16 exchange via ds_swizzle (BitMode xor=16, and=0x1F) — LDS pipe,
// result intentionally NOT consumed at issue site (deferred to next step).
__device__ __forceinline__ int swz16i(float x) {
#if __has_builtin(__builtin_amdgcn_ds_swizzle)
  return __builtin_amdgcn_ds_swizzle(__builtin_bit_cast(int, x), 0x401F);
#else
  return __builtin_bit_cast(int, __shfl_xor(x, 16));
#endif
}

__device__ __forceinline__ void read_hu(const f16* base, uint hu[16]) {
  const uint4* hq = (const uint4*)base;
  uint4 q0 = hq[0], q1 = hq[1], q2 = hq[2], q3 = hq[3];
  hu[0]=q0.x; hu[1]=q0.y; hu[2]=q0.z; hu[3]=q0.w;
  hu[4]=q1.x; hu[5]=q1.y; hu[6]=q1.z; hu[7]=q1.w;
  hu[8]=q2.x; hu[9]=q2.y; hu[10]=q2.z; hu[11]=q2.w;
  hu[12]=q3.x; hu[13]=q3.y; hu[14]=q3.z; hu[15]=q3.w;
}

// ---------------- convert: W -> MFMA-fragment-ordered f16 (WhF), R -> transposed f16 ----------------
__global__ __launch_bounds__(256) void k_convert(const float* __restrict__ Wg,
                                                 const float* __restrict__ Rg,
                                                 f16* __restrict__ WhF,
                                                 f16* __restrict__ RT) {
  int i = blockIdx.x * 256 + threadIdx.x;
  const int nWfrag = 2 * 4 * 32 * 64;   // 16384 groups of 8 f16
  if (i < nWfrag) {
    int lane = i & 63;
    int ii   = (i >> 6) & 31;
    int kk   = (i >> 11) & 3;
    int l    = i >> 13;
    int c = ii * 16 + (lane & 15);
    int d = kk * 32 + ((lane >> 4) << 3);
    const float* src = Wg + ((size_t)(l * 512 + c) * 128 + d);
    f16* dst = WhF + (size_t)i * 8;
    #pragma unroll
    for (int j = 0; j < 8; ++j) dst[j] = (f16)src[j];
  } else {
    int j = i - nWfrag;  // 32768 = 2*4*4*32*32
    if (j < 32768) {
      int dd = j & 31;
      int e  = (j >> 5) & 31;
      int hh = (j >> 10) & 3;
      int g  = (j >> 12) & 3;
      int l  = j >> 14;
      RT[j] = (f16)Rg[((((l * 4 + g) * 4 + hh) * 32 + dd) * 32) + e];
    }
  }
}

// ---------------- GEMM: column-split B-resident, inline LayerNorm ----------------
// r6 structure with the j-dimension externalized to the grid: block pair
// (bx, cy) covers rows bx*128 and column half cy. Wave w owns output cols
// i7 = w + 4*cy (+{0,8,16,24} gate offsets) — bregs shrink 128->64 VGPR and
// LN weights are reloaded per tile (L1-hot) instead of preloaded (-64 VGPR),
// roughly doubling resident waves for this latency-bound kernel. Per-column
// FP arithmetic is bit-identical to r6.
template<int EMB>
__global__ __launch_bounds__(256, 2) void k_gemm(const float* __restrict__ xsrc,
                                                 const int* __restrict__ ids,
                                                 const float* __restrict__ lw,
                                                 const float* __restrict__ lb,
                                                 const f16* __restrict__ WhF,
                                                 const float* __restrict__ bias,
                                                 uint2* __restrict__ preP) {
  int w = threadIdx.x >> 6;
  int lane = threadIdx.x & 63;
  int l16 = lane & 15, quad = lane >> 4;
  int bx = blockIdx.x >> 1;
  int cy = blockIdx.x & 1;          // column half (low bit: pairs share A rows)
  int m_base = bx * 128;
  int i7 = w + 4 * cy;              // this wave's packed-column index 0..7

  // resident B fragments: [g][kk], i = i7 + 8g  (64 VGPR)
  f16x8 bregs[4][4];
  #pragma unroll
  for (int g = 0; g < 4; ++g) {
    int i = i7 + 8 * g;
    #pragma unroll
    for (int kk = 0; kk < 4; ++kk)
      bregs[g][kk] = *(const f16x8*)(WhF + (size_t)(kk * 32 + i) * 512 + lane * 8);
  }
  float bv[4];
  #pragma unroll
  for (int g = 0; g < 4; ++g)
    bv[g] = bias[(i7 + 8 * g) * 16 + l16];

  #pragma unroll 1
  for (int t16 = 0; t16 < 8; ++t16) {
    int m0 = m_base + t16 * 16;

    const float* src;
    if (EMB) src = xsrc + (size_t)ids[m0 + l16] * Dn;
    else     src = xsrc + (size_t)(m0 + l16) * Dn;
    const float* sp = src + quad * 8;

    f32x4 v[4][2];
    #pragma unroll
    for (int kk = 0; kk < 4; ++kk) {
      v[kk][0] = *(const f32x4*)(sp + kk * 32);
      v[kk][1] = *(const f32x4*)(sp + kk * 32 + 4);
    }
    float s1 = 0.f, s2 = 0.f;
    #pragma unroll
    for (int kk = 0; kk < 4; ++kk)
      #pragma unroll
      for (int p = 0; p < 2; ++p)
        #pragma unroll
        for (int j = 0; j < 4; ++j) {
          float vv = v[kk][p][j];
          s1 += vv; s2 = fmaf(vv, vv, s2);
        }
    s1 += __shfl_xor(s1, 16);  s2 += __shfl_xor(s2, 16);
    s1 += __shfl_xor(s1, 32);  s2 += __shfl_xor(s2, 32);
    float mu = s1 * (1.f / 128.f);
    float var = s2 * (1.f / 128.f) - mu * mu;
    float rs = rsqrtf(var + 1e-5f);

    // normalize -> f16 fragments (lw/lb reloaded per tile: L1-hot)
    f16x8 a[4];
    #pragma unroll
    for (int kk = 0; kk < 4; ++kk)
      #pragma unroll
      for (int p = 0; p < 2; ++p) {
        int d0 = kk * 32 + quad * 8 + p * 4;
        f32x4 lw4 = *(const f32x4*)(lw + d0);
        f32x4 lb4 = *(const f32x4*)(lb + d0);
        #pragma unroll
        for (int j = 0; j < 4; ++j)
          a[kk][p * 4 + j] = (f16)((v[kk][p][j] - mu) * rs * lw4[j] + lb4[j]);
      }

    f32x4 acc[4] = {};
    #pragma unroll
    for (int kk = 0; kk < 4; ++kk)
      #pragma unroll
      for (int g = 0; g < 4; ++g)
        acc[g] = __builtin_amdgcn_mfma_f32_16x16x32_f16(a[kk], bregs[g][kk], acc[g], 0, 0, 0);

    #pragma unroll
    for (int r = 0; r < 4; ++r) {
      int m = m0 + quad * 4 + r;
      uint2 vv;
      vv.x = pk2(acc[0][r] + bv[0], acc[1][r] + bv[1]);
      vv.y = pk2(acc[2][r] + bv[2], acc[3][r] + bv[3]);
      preP[(size_t)m * Dn + i7 * 16 + l16] = vv;
    }
  }
}

// ---------------- fused scan (r4 pipelined schedule, unchanged math) ----------------
// LAST=0 (layer 0): residual x gathered directly from emb[ids[t]] per step;
//                   writes xout = x1.
// LAST=1 (layer 1): residual from x1; mean-pool accumulated in-register; head
//                   MLP (128->64 relu ->2) computed in the epilogue via LDS.
template<int LAST>
__global__ __launch_bounds__(256, 1) void k_scan(const uint2* __restrict__ preP,
                                                 const f16* __restrict__ RT,
                                                 const float* __restrict__ gnw,
                                                 const float* __restrict__ xsrc,
                                                 const int* __restrict__ ids,
                                                 float* __restrict__ xout,
                                                 const float* __restrict__ hw1,
                                                 const float* __restrict__ hb1,
                                                 const float* __restrict__ hw2,
                                                 const float* __restrict__ hb2,
                                                 float* __restrict__ out) {
  const int w = threadIdx.x >> 6;       // wave 0..3
  const int lane = threadIdx.x & 63;
  const int s = w >> 1;                 // seq within block
  const int b = blockIdx.x * 2 + s;
  const int d = ((w & 1) << 6) + lane;  // element 0..127 of this seq
  const int head = d >> 5;
  const int e = d & 31;
  const int half = lane >> 5;

  __shared__ __align__(16) f16 hsh[4][64];   // per-wave h exchange
  __shared__ float pool2[2][128];            // LAST: pooled rows
  __shared__ float hid2[2][64];              // LAST: hidden layer

  uint rr[4][16];
  const uint* RT32 = (const uint*)RT;
  #pragma unroll
  for (int g = 0; g < 4; ++g) {
    const uint* p = RT32 + ((g * 4 + head) * 32 + e) * 16;
    #pragma unroll
    for (int j = 0; j < 16; ++j) rr[g][j] = p[j];
  }
  const float gw = gnw[d];
  const f16* hbase = &hsh[w][half * 32];   // my head-group's 32 h values

  hsh[w][lane] = (f16)0.f;   // wave-local, DS in-order

  const uint2* pp = preP + (size_t)b * Ln * Dn + d;   // + t*Dn
  const float* xp = xsrc + (size_t)b * Ln * Dn + d;   // LAST=1 residual path
  const int*   idr = ids + b * Ln;                    // LAST=0 gather path
  float* xo = xout + (size_t)b * Ln * Dn + d;

  // 4-deep prefetch pipeline (preP overrun stays inside workspace)
  uint2 pb[4]; float xb[4]; int idb[4];
  #pragma unroll
  for (int k = 0; k < 4; ++k) {
    pb[k] = pp[(size_t)k * Dn];
    if (LAST) {
      xb[k] = xp[(size_t)k * Dn];
    } else {
      xb[k] = xsrc[(size_t)idr[k] * Dn + d];
      idb[k] = idr[k + 4];
    }
  }

  // preheader: hu for t=0 (all zeros, but read keeps the pipeline uniform)
  uint hu[16];
  read_hu(hbase, hu);

  float cc = 0.f, nc = 0.f, mc = 0.f, psum = 0.f;
  float hprev = 0.f, xprev = 0.f;
  float u1 = 0.f, u2 = 0.f;   // 16-row partial GN sums of step t-1
  int   w1 = 0,   w2 = 0;     // raw ds_swizzle results (other 16-row sums)

  #pragma unroll 1
  for (int t = 0; t < Ln; t += 4) {
    #pragma unroll
    for (int k = 0; k < 4; ++k) {
      int tt = t + k;
      uint2 pc = pb[k]; float xc = xb[k];
      pb[k] = pp[(size_t)(tt + 4) * Dn];
      if (LAST) {
        xb[k] = xp[(size_t)(tt + 4) * Dn];
      } else {
        xb[k] = xsrc[(size_t)idb[k] * Dn + d];
        int ni = tt + 8;
        idb[k] = idr[ni > 127 ? 127 : ni];
      }

      // GN of step tt-1: combine deferred swizzle halves here
      if (tt > 0) {
        float s1 = u1 + __builtin_bit_cast(float, w1);
        float s2 = u2 + __builtin_bit_cast(float, w2);
        float mu = s1 * (1.f / 32.f);
        float va = s2 * (1.f / 32.f) - mu * mu;
        float ov = xprev + (hprev - mu) * rsqrtf(va + 1e-5f) * gw;
        if (LAST) psum += ov;
        else      xo[(size_t)(tt - 1) * Dn] = ov;
      }

      // recurrence dot products: 8 chains of 8 (2-way split per gate)
      float a0 = 0.f, a1 = 0.f, a2 = 0.f, a3 = 0.f;
      float c0 = 0.f, c1 = 0.f, c2 = 0.f, c3 = 0.f;
      #pragma unroll
      for (int j = 0; j < 8; ++j) {
        a0 = fdot2f(hu[j], rr[0][j], a0);
        a1 = fdot2f(hu[j], rr[1][j], a1);
        a2 = fdot2f(hu[j], rr[2][j], a2);
        a3 = fdot2f(hu[j], rr[3][j], a3);
        c0 = fdot2f(hu[j + 8], rr[0][j + 8], c0);
        c1 = fdot2f(hu[j + 8], rr[1][j + 8], c1);
        c2 = fdot2f(hu[j + 8], rr[2][j + 8], c2);
        c3 = fdot2f(hu[j + 8], rr[3][j + 8], c3);
      }
      f16x2 lo = __builtin_bit_cast(f16x2, pc.x);
      f16x2 hi = __builtin_bit_cast(f16x2, pc.y);
      float it = ((float)lo[0] + a0) + c0;
      float ft = ((float)lo[1] + a1) + c1;
      float zt = ((float)hi[0] + a2) + c2;
      float ot = ((float)hi[1] + a3) + c3;

      float mn = fmaxf(ft + mc, it);
      float iv = __expf(it - mn);
      float fv = __expf(ft + mc - mn);
      float zc = fminf(fmaxf(zt, -15.f), 15.f);
      float ez = __expf(2.f * zc);
      float tz = (ez - 1.f) * __builtin_amdgcn_rcpf(ez + 1.f);
      float cn = fv * cc + iv * tz;
      float nn = fv * nc + iv;
      // h = sigmoid(ot) * c / n = c / ((1 + exp(-ot)) * n)  — single rcp
      float hn = cn * __builtin_amdgcn_rcpf((1.f + __expf(-ot)) * nn);
      cc = cn; nc = nn; mc = mn;

      // --- DS schedule for next step (issue-only, no consumption here) ---
      hsh[w][lane] = (f16)hn;                       // DS op 1: h exchange

      float t1v = hn, t2v = hn * hn;                // VALU rors: 16-row sums
      t1v += rorf<0x121>(t1v);  t2v += rorf<0x121>(t2v);   // ror 1
      t1v += rorf<0x122>(t1v);  t2v += rorf<0x122>(t2v);   // ror 2
      t1v += rorf<0x124>(t1v);  t2v += rorf<0x124>(t2v);   // ror 4
      t1v += rorf<0x128>(t1v);  t2v += rorf<0x128>(t2v);   // ror 8
      w1 = swz16i(t1v);                             // DS ops 2,3: xor-16
      w2 = swz16i(t2v);                             //   (combined next step)
      u1 = t1v; u2 = t2v;

      read_hu(hbase, hu);                           // DS ops 4..7: hu for t+1

      hprev = hn; xprev = xc;
    }
  }

  // epilogue: groupnorm of step 127
  {
    float s1 = u1 + __builtin_bit_cast(float, w1);
    float s2 = u2 + __builtin_bit_cast(float, w2);
    float mu = s1 * (1.f / 32.f);
    float va = s2 * (1.f / 32.f) - mu * mu;
    float ov = xprev + (hprev - mu) * rsqrtf(va + 1e-5f) * gw;
    if (LAST) {
      psum += ov;
      pool2[s][d] = psum * (1.f / 128.f);
      __syncthreads();
      // head MLP: waves 0,2 handle local seqs 0,1
      if ((w & 1) == 0) {
        int sq = w >> 1;
        float acc = hb1[lane];
        const float* wr = hw1 + (size_t)lane * Dn;
        const float* pl = &pool2[sq][0];
        #pragma unroll 8
        for (int dd = 0; dd < Dn; dd += 4) {
          f32x4 wv = *(const f32x4*)(wr + dd);
          acc += wv[0]*pl[dd] + wv[1]*pl[dd+1] + wv[2]*pl[dd+2] + wv[3]*pl[dd+3];
        }
        hid2[sq][lane] = fmaxf(acc, 0.f);
      }
      __syncthreads();
      if ((w & 1) == 0 && lane < 2) {
        int sq = w >> 1;
        float acc = hb2[lane];
        const float* wr = hw2 + lane * 64;
        #pragma unroll 4
        for (int j = 0; j < 64; ++j) acc += hid2[sq][j] * wr[j];
        out[(blockIdx.x * 2 + sq) * 2 + lane] = acc;
      }
    } else {
      xo[(size_t)(Ln - 1) * Dn] = ov;
    }
  }
}

extern "C" void kernel_launch(void* const* d_in, const int* in_sizes, int n_in,
                              void* d_out, int out_size, void* d_ws, size_t ws_size,
                              hipStream_t stream) {
  const int*   ids  = (const int*)d_in[0];
  const float* emb  = (const float*)d_in[1];
  const float* ln_w = (const float*)d_in[2];
  const float* ln_b = (const float*)d_in[3];
  const float* Wg   = (const float*)d_in[4];
  const float* Rg   = (const float*)d_in[5];
  const float* bg   = (const float*)d_in[6];
  const float* gn_w = (const float*)d_in[7];
  const float* w1   = (const float*)d_in[8];
  const float* b1   = (const float*)d_in[9];
  const float* w2   = (const float*)d_in[10];
  const float* b2   = (const float*)d_in[11];
  float* out = (float*)d_out;

  char* ws = (char*)d_ws;
  uint2* preP = (uint2*)ws;                        // 67,108,864 B
  float* x1   = (float*)(ws + 67108864);           // 33,554,432 B
  f16*   WhF  = (f16*)(ws + 100663296);            //    262,144 B
  f16*   RT   = (f16*)(ws + 100663296 + 262144);   //     65,536 B

  k_convert<<<192, 256, 0, stream>>>(Wg, Rg, WhF, RT);

  // layer 0: gather+LN fused into GEMM; scan gathers residual from emb directly
  k_gemm<1><<<1024, 256, 0, stream>>>(emb, ids, ln_w, ln_b, WhF, bg, preP);
  k_scan<0><<<256, 256, 0, stream>>>(preP, RT, gn_w, emb, ids, x1,
                                     nullptr, nullptr, nullptr, nullptr, nullptr);
  // layer 1: LN fused into GEMM; head MLP fused into scan epilogue
  k_gemm<0><<<1024, 256, 0, stream>>>(x1, nullptr, ln_w + Dn, ln_b + Dn,
                                      WhF + 65536, bg + Cn, preP);
  k_scan<1><<<256, 256, 0, stream>>>(preP, RT + 16384, gn_w + Dn, x1, nullptr,
                                     nullptr, w1, b1, w2, b2, out);
}

// Round 13
// 228.679 us; speedup vs baseline: 2.4642x; 1.1336x over previous
//
#include <hip/hip_runtime.h>

typedef _Float16 f16;
typedef unsigned int uint;
typedef f16 f16x2 __attribute__((ext_vector_type(2)));
typedef f16 f16x8 __attribute__((ext_vector_type(8)));
typedef __fp16 h16x2 __attribute__((ext_vector_type(2)));
typedef float f32x4 __attribute__((ext_vector_type(4)));

#define Bn 512
#define Ln 128
#define Dn 128
#define Cn 512   // 4 gates * D

__device__ __forceinline__ float fdot2f(uint a, uint b, float c) {
#if __has_builtin(__builtin_amdgcn_fdot2)
  return __builtin_amdgcn_fdot2(__builtin_bit_cast(f16x2, a),
                                __builtin_bit_cast(f16x2, b), c, false);
#else
  f16x2 av = __builtin_bit_cast(f16x2, a), bv = __builtin_bit_cast(f16x2, b);
  return c + (float)av[0] * (float)bv[0] + (float)av[1] * (float)bv[1];
#endif
}

__device__ __forceinline__ uint pk2(float a, float b) {
#if __has_builtin(__builtin_amdgcn_cvt_pkrtz)
  h16x2 v = __builtin_amdgcn_cvt_pkrtz(a, b);
  return __builtin_bit_cast(uint, v);
#else
  f16x2 v; v[0] = (f16)a; v[1] = (f16)b;
  return __builtin_bit_cast(uint, v);
#endif
}

// DPP row_ror<N> (VALU, 2-cyc): rotational reduce within 16-lane rows.
template<int CTRL>
__device__ __forceinline__ float rorf(float x) {
#if __has_builtin(__builtin_amdgcn_mov_dpp)
  int r = __builtin_amdgcn_mov_dpp(__builtin_bit_cast(int, x), CTRL, 0xF, 0xF, true);
  return __builtin_bit_cast(float, r);
#else
  return __shfl_xor(x, (CTRL - 0x120));
#endif
}

// lane ^ 16 exchange via ds_swizzle (BitMode xor=16, and=0x1F) — LDS pipe,
// result intentionally NOT consumed at issue site (deferred to next step).
__device__ __forceinline__ int swz16i(float x) {
#if __has_builtin(__builtin_amdgcn_ds_swizzle)
  return __builtin_amdgcn_ds_swizzle(__builtin_bit_cast(int, x), 0x401F);
#else
  return __builtin_bit_cast(int, __shfl_xor(x, 16));
#endif
}

__device__ __forceinline__ void read_hu(const f16* base, uint hu[16]) {
  const uint4* hq = (const uint4*)base;
  uint4 q0 = hq[0], q1 = hq[1], q2 = hq[2], q3 = hq[3];
  hu[0]=q0.x; hu[1]=q0.y; hu[2]=q0.z; hu[3]=q0.w;
  hu[4]=q1.x; hu[5]=q1.y; hu[6]=q1.z; hu[7]=q1.w;
  hu[8]=q2.x; hu[9]=q2.y; hu[10]=q2.z; hu[11]=q2.w;
  hu[12]=q3.x; hu[13]=q3.y; hu[14]=q3.z; hu[15]=q3.w;
}

// ---------------- convert: W -> MFMA-fragment-ordered f16 (WhF), R -> transposed f16 ----------------
__global__ __launch_bounds__(256) void k_convert(const float* __restrict__ Wg,
                                                 const float* __restrict__ Rg,
                                                 f16* __restrict__ WhF,
                                                 f16* __restrict__ RT) {
  int i = blockIdx.x * 256 + threadIdx.x;
  const int nWfrag = 2 * 4 * 32 * 64;   // 16384 groups of 8 f16
  if (i < nWfrag) {
    int lane = i & 63;
    int ii   = (i >> 6) & 31;
    int kk   = (i >> 11) & 3;
    int l    = i >> 13;
    int c = ii * 16 + (lane & 15);
    int d = kk * 32 + ((lane >> 4) << 3);
    const float* src = Wg + ((size_t)(l * 512 + c) * 128 + d);
    f16* dst = WhF + (size_t)i * 8;
    #pragma unroll
    for (int j = 0; j < 8; ++j) dst[j] = (f16)src[j];
  } else {
    int j = i - nWfrag;  // 32768 = 2*4*4*32*32
    if (j < 32768) {
      int dd = j & 31;
      int e  = (j >> 5) & 31;
      int hh = (j >> 10) & 3;
      int g  = (j >> 12) & 3;
      int l  = j >> 14;
      RT[j] = (f16)Rg[((((l * 4 + g) * 4 + hh) * 32 + dd) * 32) + e];
    }
  }
}

// ---------------- GEMM, B-resident-in-registers, inline LayerNorm ----------------
// Wave w owns output cols i in {2w,2w+1}+{0,8,16,24} — exactly the 8 i-values
// its gate-packed uint2 stores need. Its 32 B-fragments (128 VGPR) are loaded
// ONCE per block, then 8 m-tiles of 16 rows stream through: A-load+LN -> 32
// MFMA (register B, no loads) -> 8 packed stores. (Session-verified optimum:
// register prefetch spills [r9], async LDS staging races [r11], column-split
// doubles A-gather traffic [r12] — leave this structure alone.)
template<int EMB>
__global__ __launch_bounds__(256, 2) void k_gemm(const float* __restrict__ xsrc,
                                                 const int* __restrict__ ids,
                                                 const float* __restrict__ lw,
                                                 const float* __restrict__ lb,
                                                 const f16* __restrict__ WhF,
                                                 const float* __restrict__ bias,
                                                 uint2* __restrict__ preP) {
  int w = threadIdx.x >> 6;
  int lane = threadIdx.x & 63;
  int l16 = lane & 15, quad = lane >> 4;

  // resident B fragments: [j][g][kk], i = 2w + j + 8g
  f16x8 bregs[2][4][4];
  #pragma unroll
  for (int j = 0; j < 2; ++j)
    #pragma unroll
    for (int g = 0; g < 4; ++g) {
      int i = 2 * w + j + 8 * g;
      #pragma unroll
      for (int kk = 0; kk < 4; ++kk)
        bregs[j][g][kk] = *(const f16x8*)(WhF + (size_t)(kk * 32 + i) * 512 + lane * 8);
    }
  float bv[2][4];
  #pragma unroll
  for (int j = 0; j < 2; ++j)
    #pragma unroll
    for (int g = 0; g < 4; ++g)
      bv[j][g] = bias[(2 * w + j + 8 * g) * 16 + l16];

  // LN weight slice for this lane (dims kk*32 + quad*8 + 0..7)
  f32x4 lw4[4][2], lb4[4][2];
  #pragma unroll
  for (int kk = 0; kk < 4; ++kk)
    #pragma unroll
    for (int p = 0; p < 2; ++p) {
      int d0 = kk * 32 + quad * 8 + p * 4;
      lw4[kk][p] = *(const f32x4*)(lw + d0);
      lb4[kk][p] = *(const f32x4*)(lb + d0);
    }

  #pragma unroll 1
  for (int t16 = 0; t16 < 8; ++t16) {
    int m0 = blockIdx.x * 128 + t16 * 16;

    const float* src;
    if (EMB) src = xsrc + (size_t)ids[m0 + l16] * Dn;
    else     src = xsrc + (size_t)(m0 + l16) * Dn;
    const float* sp = src + quad * 8;

    f32x4 v[4][2];
    #pragma unroll
    for (int kk = 0; kk < 4; ++kk) {
      v[kk][0] = *(const f32x4*)(sp + kk * 32);
      v[kk][1] = *(const f32x4*)(sp + kk * 32 + 4);
    }
    float s1 = 0.f, s2 = 0.f;
    #pragma unroll
    for (int kk = 0; kk < 4; ++kk)
      #pragma unroll
      for (int p = 0; p < 2; ++p)
        #pragma unroll
        for (int j = 0; j < 4; ++j) {
          float vv = v[kk][p][j];
          s1 += vv; s2 = fmaf(vv, vv, s2);
        }
    s1 += __shfl_xor(s1, 16);  s2 += __shfl_xor(s2, 16);
    s1 += __shfl_xor(s1, 32);  s2 += __shfl_xor(s2, 32);
    float mu = s1 * (1.f / 128.f);
    float var = s2 * (1.f / 128.f) - mu * mu;
    float rs = rsqrtf(var + 1e-5f);

    f16x8 a[4];
    #pragma unroll
    for (int kk = 0; kk < 4; ++kk)
      #pragma unroll
      for (int p = 0; p < 2; ++p)
        #pragma unroll
        for (int j = 0; j < 4; ++j)
          a[kk][p * 4 + j] = (f16)((v[kk][p][j] - mu) * rs * lw4[kk][p][j] + lb4[kk][p][j]);

    f32x4 acc[2][4] = {};
    #pragma unroll
    for (int kk = 0; kk < 4; ++kk)
      #pragma unroll
      for (int j = 0; j < 2; ++j)
        #pragma unroll
        for (int g = 0; g < 4; ++g)
          acc[j][g] = __builtin_amdgcn_mfma_f32_16x16x32_f16(a[kk], bregs[j][g][kk], acc[j][g], 0, 0, 0);

    #pragma unroll
    for (int r = 0; r < 4; ++r) {
      int m = m0 + quad * 4 + r;
      #pragma unroll
      for (int j = 0; j < 2; ++j) {
        uint2 vv;
        vv.x = pk2(acc[j][0][r] + bv[j][0], acc[j][1][r] + bv[j][1]);
        vv.y = pk2(acc[j][2][r] + bv[j][2], acc[j][3][r] + bv[j][3]);
        preP[(size_t)m * Dn + (2 * w + j) * 16 + l16] = vv;
      }
    }
  }
}

// ---------------- fused scan (r4 pipelined schedule, unchanged math) ----------------
// LAST=0 (layer 0): residual x gathered directly from emb[ids[t]] per step;
//                   writes xout = x1.
// LAST=1 (layer 1): residual from x1; mean-pool accumulated in-register; head
//                   MLP (128->64 relu ->2) computed in the epilogue via LDS.
template<int LAST>
__global__ __launch_bounds__(256, 1) void k_scan(const uint2* __restrict__ preP,
                                                 const f16* __restrict__ RT,
                                                 const float* __restrict__ gnw,
                                                 const float* __restrict__ xsrc,
                                                 const int* __restrict__ ids,
                                                 float* __restrict__ xout,
                                                 const float* __restrict__ hw1,
                                                 const float* __restrict__ hb1,
                                                 const float* __restrict__ hw2,
                                                 const float* __restrict__ hb2,
                                                 float* __restrict__ out) {
  const int w = threadIdx.x >> 6;       // wave 0..3
  const int lane = threadIdx.x & 63;
  const int s = w >> 1;                 // seq within block
  const int b = blockIdx.x * 2 + s;
  const int d = ((w & 1) << 6) + lane;  // element 0..127 of this seq
  const int head = d >> 5;
  const int e = d & 31;
  const int half = lane >> 5;

  __shared__ __align__(16) f16 hsh[4][64];   // per-wave h exchange
  __shared__ float pool2[2][128];            // LAST: pooled rows
  __shared__ float hid2[2][64];              // LAST: hidden layer

  uint rr[4][16];
  const uint* RT32 = (const uint*)RT;
  #pragma unroll
  for (int g = 0; g < 4; ++g) {
    const uint* p = RT32 + ((g * 4 + head) * 32 + e) * 16;
    #pragma unroll
    for (int j = 0; j < 16; ++j) rr[g][j] = p[j];
  }
  const float gw = gnw[d];
  const f16* hbase = &hsh[w][half * 32];   // my head-group's 32 h values

  hsh[w][lane] = (f16)0.f;   // wave-local, DS in-order

  const uint2* pp = preP + (size_t)b * Ln * Dn + d;   // + t*Dn
  const float* xp = xsrc + (size_t)b * Ln * Dn + d;   // LAST=1 residual path
  const int*   idr = ids + b * Ln;                    // LAST=0 gather path
  float* xo = xout + (size_t)b * Ln * Dn + d;

  // 4-deep prefetch pipeline (preP overrun stays inside workspace)
  uint2 pb[4]; float xb[4]; int idb[4];
  #pragma unroll
  for (int k = 0; k < 4; ++k) {
    pb[k] = pp[(size_t)k * Dn];
    if (LAST) {
      xb[k] = xp[(size_t)k * Dn];
    } else {
      xb[k] = xsrc[(size_t)idr[k] * Dn + d];
      idb[k] = idr[k + 4];
    }
  }

  // preheader: hu for t=0 (all zeros, but read keeps the pipeline uniform)
  uint hu[16];
  read_hu(hbase, hu);

  float cc = 0.f, nc = 0.f, mc = 0.f, psum = 0.f;
  float hprev = 0.f, xprev = 0.f;
  float u1 = 0.f, u2 = 0.f;   // 16-row partial GN sums of step t-1
  int   w1 = 0,   w2 = 0;     // raw ds_swizzle results (other 16-row sums)

  #pragma unroll 1
  for (int t = 0; t < Ln; t += 4) {
    #pragma unroll
    for (int k = 0; k < 4; ++k) {
      int tt = t + k;
      uint2 pc = pb[k]; float xc = xb[k];
      pb[k] = pp[(size_t)(tt + 4) * Dn];
      if (LAST) {
        xb[k] = xp[(size_t)(tt + 4) * Dn];
      } else {
        xb[k] = xsrc[(size_t)idb[k] * Dn + d];
        int ni = tt + 8;
        idb[k] = idr[ni > 127 ? 127 : ni];
      }

      // GN of step tt-1: combine deferred swizzle halves here
      if (tt > 0) {
        float s1 = u1 + __builtin_bit_cast(float, w1);
        float s2 = u2 + __builtin_bit_cast(float, w2);
        float mu = s1 * (1.f / 32.f);
        float va = s2 * (1.f / 32.f) - mu * mu;
        float ov = xprev + (hprev - mu) * rsqrtf(va + 1e-5f) * gw;
        if (LAST) psum += ov;
        else      xo[(size_t)(tt - 1) * Dn] = ov;
      }

      // recurrence dot products: 8 chains of 8 (2-way split per gate)
      float a0 = 0.f, a1 = 0.f, a2 = 0.f, a3 = 0.f;
      float c0 = 0.f, c1 = 0.f, c2 = 0.f, c3 = 0.f;
      #pragma unroll
      for (int j = 0; j < 8; ++j) {
        a0 = fdot2f(hu[j], rr[0][j], a0);
        a1 = fdot2f(hu[j], rr[1][j], a1);
        a2 = fdot2f(hu[j], rr[2][j], a2);
        a3 = fdot2f(hu[j], rr[3][j], a3);
        c0 = fdot2f(hu[j + 8], rr[0][j + 8], c0);
        c1 = fdot2f(hu[j + 8], rr[1][j + 8], c1);
        c2 = fdot2f(hu[j + 8], rr[2][j + 8], c2);
        c3 = fdot2f(hu[j + 8], rr[3][j + 8], c3);
      }
      f16x2 lo = __builtin_bit_cast(f16x2, pc.x);
      f16x2 hi = __builtin_bit_cast(f16x2, pc.y);
      float it = ((float)lo[0] + a0) + c0;
      float ft = ((float)lo[1] + a1) + c1;
      float zt = ((float)hi[0] + a2) + c2;
      float ot = ((float)hi[1] + a3) + c3;

      float mn = fmaxf(ft + mc, it);
      float iv = __expf(it - mn);
      float fv = __expf(ft + mc - mn);
      float zc = fminf(fmaxf(zt, -15.f), 15.f);
      float ez = __expf(2.f * zc);
      float tz = (ez - 1.f) * __builtin_amdgcn_rcpf(ez + 1.f);
      float cn = fv * cc + iv * tz;
      float nn = fv * nc + iv;
      // h = sigmoid(ot) * c / n = c / ((1 + exp(-ot)) * n)  — single rcp
      float hn = cn * __builtin_amdgcn_rcpf((1.f + __expf(-ot)) * nn);
      cc = cn; nc = nn; mc = mn;

      // --- DS schedule for next step (issue-only, no consumption here) ---
      hsh[w][lane] = (f16)hn;                       // DS op 1: h exchange

      float t1v = hn, t2v = hn * hn;                // VALU rors: 16-row sums
      t1v += rorf<0x121>(t1v);  t2v += rorf<0x121>(t2v);   // ror 1
      t1v += rorf<0x122>(t1v);  t2v += rorf<0x122>(t2v);   // ror 2
      t1v += rorf<0x124>(t1v);  t2v += rorf<0x124>(t2v);   // ror 4
      t1v += rorf<0x128>(t1v);  t2v += rorf<0x128>(t2v);   // ror 8
      w1 = swz16i(t1v);                             // DS ops 2,3: xor-16
      w2 = swz16i(t2v);                             //   (combined next step)
      u1 = t1v; u2 = t2v;

      read_hu(hbase, hu);                           // DS ops 4..7: hu for t+1

      hprev = hn; xprev = xc;
    }
  }

  // epilogue: groupnorm of step 127
  {
    float s1 = u1 + __builtin_bit_cast(float, w1);
    float s2 = u2 + __builtin_bit_cast(float, w2);
    float mu = s1 * (1.f / 32.f);
    float va = s2 * (1.f / 32.f) - mu * mu;
    float ov = xprev + (hprev - mu) * rsqrtf(va + 1e-5f) * gw;
    if (LAST) {
      psum += ov;
      pool2[s][d] = psum * (1.f / 128.f);
      __syncthreads();
      // head MLP: waves 0,2 handle local seqs 0,1
      if ((w & 1) == 0) {
        int sq = w >> 1;
        float acc = hb1[lane];
        const float* wr = hw1 + (size_t)lane * Dn;
        const float* pl = &pool2[sq][0];
        #pragma unroll 8
        for (int dd = 0; dd < Dn; dd += 4) {
          f32x4 wv = *(const f32x4*)(wr + dd);
          acc += wv[0]*pl[dd] + wv[1]*pl[dd+1] + wv[2]*pl[dd+2] + wv[3]*pl[dd+3];
        }
        hid2[sq][lane] = fmaxf(acc, 0.f);
      }
      __syncthreads();
      if ((w & 1) == 0 && lane < 2) {
        int sq = w >> 1;
        float acc = hb2[lane];
        const float* wr = hw2 + lane * 64;
        #pragma unroll 4
        for (int j = 0; j < 64; ++j) acc += hid2[sq][j] * wr[j];
        out[(blockIdx.x * 2 + sq) * 2 + lane] = acc;
      }
    } else {
      xo[(size_t)(Ln - 1) * Dn] = ov;
    }
  }
}

extern "C" void kernel_launch(void* const* d_in, const int* in_sizes, int n_in,
                              void* d_out, int out_size, void* d_ws, size_t ws_size,
                              hipStream_t stream) {
  const int*   ids  = (const int*)d_in[0];
  const float* emb  = (const float*)d_in[1];
  const float* ln_w = (const float*)d_in[2];
  const float* ln_b = (const float*)d_in[3];
  const float* Wg   = (const float*)d_in[4];
  const float* Rg   = (const float*)d_in[5];
  const float* bg   = (const float*)d_in[6];
  const float* gn_w = (const float*)d_in[7];
  const float* w1   = (const float*)d_in[8];
  const float* b1   = (const float*)d_in[9];
  const float* w2   = (const float*)d_in[10];
  const float* b2   = (const float*)d_in[11];
  float* out = (float*)d_out;

  char* ws = (char*)d_ws;
  uint2* preP = (uint2*)ws;                        // 67,108,864 B
  float* x1   = (float*)(ws + 67108864);           // 33,554,432 B
  f16*   WhF  = (f16*)(ws + 100663296);            //    262,144 B
  f16*   RT   = (f16*)(ws + 100663296 + 262144);   //     65,536 B

  k_convert<<<192, 256, 0, stream>>>(Wg, Rg, WhF, RT);

  // layer 0: gather+LN fused into GEMM; scan gathers residual from emb directly
  k_gemm<1><<<512, 256, 0, stream>>>(emb, ids, ln_w, ln_b, WhF, bg, preP);
  k_scan<0><<<256, 256, 0, stream>>>(preP, RT, gn_w, emb, ids, x1,
                                     nullptr, nullptr, nullptr, nullptr, nullptr);
  // layer 1: LN fused into GEMM; head MLP fused into scan epilogue
  k_gemm<0><<<512, 256, 0, stream>>>(x1, nullptr, ln_w + Dn, ln_b + Dn,
                                     WhF + 65536, bg + Cn, preP);
  k_scan<1><<<256, 256, 0, stream>>>(preP, RT + 16384, gn_w + Dn, x1, nullptr,
                                     nullptr, w1, b1, w2, b2, out);
}

// Round 15
// 220.023 us; speedup vs baseline: 2.5612x; 1.0393x over previous
//
#include <hip/hip_runtime.h>

typedef _Float16 f16;
typedef unsigned int uint;
typedef f16 f16x2 __attribute__((ext_vector_type(2)));
typedef f16 f16x8 __attribute__((ext_vector_type(8)));
typedef __fp16 h16x2 __attribute__((ext_vector_type(2)));
typedef float f32x4 __attribute__((ext_vector_type(4)));

#define Bn 512
#define Ln 128
#define Dn 128
#define Cn 512   // 4 gates * D

__device__ __forceinline__ float fdot2f(uint a, uint b, float c) {
#if __has_builtin(__builtin_amdgcn_fdot2)
  return __builtin_amdgcn_fdot2(__builtin_bit_cast(f16x2, a),
                                __builtin_bit_cast(f16x2, b), c, false);
#else
  f16x2 av = __builtin_bit_cast(f16x2, a), bv = __builtin_bit_cast(f16x2, b);
  return c + (float)av[0] * (float)bv[0] + (float)av[1] * (float)bv[1];
#endif
}

__device__ __forceinline__ uint pk2(float a, float b) {
#if __has_builtin(__builtin_amdgcn_cvt_pkrtz)
  h16x2 v = __builtin_amdgcn_cvt_pkrtz(a, b);
  return __builtin_bit_cast(uint, v);
#else
  f16x2 v; v[0] = (f16)a; v[1] = (f16)b;
  return __builtin_bit_cast(uint, v);
#endif
}

// DPP row_ror<N> (VALU, 2-cyc): rotational reduce within 16-lane rows.
template<int CTRL>
__device__ __forceinline__ float rorf(float x) {
#if __has_builtin(__builtin_amdgcn_mov_dpp)
  int r = __builtin_amdgcn_mov_dpp(__builtin_bit_cast(int, x), CTRL, 0xF, 0xF, true);
  return __builtin_bit_cast(float, r);
#else
  return __shfl_xor(x, (CTRL - 0x120));
#endif
}

// lane ^ 16 exchange via ds_swizzle (BitMode xor=16, and=0x1F) — LDS pipe,
// result intentionally NOT consumed at issue site (deferred to next step).
__device__ __forceinline__ int swz16i(float x) {
#if __has_builtin(__builtin_amdgcn_ds_swizzle)
  return __builtin_amdgcn_ds_swizzle(__builtin_bit_cast(int, x), 0x401F);
#else
  return __builtin_bit_cast(int, __shfl_xor(x, 16));
#endif
}

__device__ __forceinline__ void read_hu(const f16* base, uint hu[16]) {
  const uint4* hq = (const uint4*)base;
  uint4 q0 = hq[0], q1 = hq[1], q2 = hq[2], q3 = hq[3];
  hu[0]=q0.x; hu[1]=q0.y; hu[2]=q0.z; hu[3]=q0.w;
  hu[4]=q1.x; hu[5]=q1.y; hu[6]=q1.z; hu[7]=q1.w;
  hu[8]=q2.x; hu[9]=q2.y; hu[10]=q2.z; hu[11]=q2.w;
  hu[12]=q3.x; hu[13]=q3.y; hu[14]=q3.z; hu[15]=q3.w;
}

// ---------------- convert: W -> MFMA-fragment-ordered f16 (WhF), R -> transposed f16 ----------------
__global__ __launch_bounds__(256) void k_convert(const float* __restrict__ Wg,
                                                 const float* __restrict__ Rg,
                                                 f16* __restrict__ WhF,
                                                 f16* __restrict__ RT) {
  int i = blockIdx.x * 256 + threadIdx.x;
  const int nWfrag = 2 * 4 * 32 * 64;   // 16384 groups of 8 f16
  if (i < nWfrag) {
    int lane = i & 63;
    int ii   = (i >> 6) & 31;
    int kk   = (i >> 11) & 3;
    int l    = i >> 13;
    int c = ii * 16 + (lane & 15);
    int d = kk * 32 + ((lane >> 4) << 3);
    const float* src = Wg + ((size_t)(l * 512 + c) * 128 + d);
    f16* dst = WhF + (size_t)i * 8;
    #pragma unroll
    for (int j = 0; j < 8; ++j) dst[j] = (f16)src[j];
  } else {
    int j = i - nWfrag;  // 32768 = 2*4*4*32*32
    if (j < 32768) {
      int dd = j & 31;
      int e  = (j >> 5) & 31;
      int hh = (j >> 10) & 3;
      int g  = (j >> 12) & 3;
      int l  = j >> 14;
      RT[j] = (f16)Rg[((((l * 4 + g) * 4 + hh) * 32 + dd) * 32) + e];
    }
  }
}

// ---------------- GEMM: B-resident registers, FULL-depth LDS A-stage ----------------
// r6 compute structure (verified optimum) with ONE change: all 128 A-rows of
// the block are staged to LDS up front — 16 dwordx4 loads/thread issued
// back-to-back (ONE exposed gather latency per block instead of 8 serialized
// per-tile latencies; r9/r11 only pipelined 1-deep and measured null).
// Plain ds_write staging (no global_load_lds — r11's race) and no persistent
// register state (staging regs die before bregs load — r9's spill lesson).
// XOR col-swizzle (both sides) spreads the LN read pattern across banks.
template<int EMB>
__global__ __launch_bounds__(256, 2) void k_gemm(const float* __restrict__ xsrc,
                                                 const int* __restrict__ ids,
                                                 const float* __restrict__ lw,
                                                 const float* __restrict__ lb,
                                                 const f16* __restrict__ WhF,
                                                 const float* __restrict__ bias,
                                                 uint2* __restrict__ preP) {
  int tid = threadIdx.x;
  int w = tid >> 6;
  int lane = tid & 63;
  int l16 = lane & 15, quad = lane >> 4;
  int m_base = blockIdx.x * 128;

  __shared__ __align__(16) uint4 abuf[128][32];   // 64 KB: 128 rows x 32 16B-segs

  // ---- stage all 128 rows: issue all 16 gathers, then write swizzled ----
  {
    uint4 stg[16];
    #pragma unroll
    for (int s = 0; s < 16; ++s) {
      int seg = s * 256 + tid;
      int row = seg >> 5, col = seg & 31;
      const float* gp;
      if (EMB) gp = xsrc + (size_t)ids[m_base + row] * Dn + col * 4;
      else     gp = xsrc + (size_t)(m_base + row) * Dn + col * 4;
      stg[s] = *(const uint4*)gp;
    }
    #pragma unroll
    for (int s = 0; s < 16; ++s) {
      int seg = s * 256 + tid;
      int row = seg >> 5, col = seg & 31;
      int colw = (col & 24) | ((col ^ row) & 7);
      abuf[row][colw] = stg[s];
    }
  }

  // resident B fragments: [j][g][kk], i = 2w + j + 8g
  f16x8 bregs[2][4][4];
  #pragma unroll
  for (int j = 0; j < 2; ++j)
    #pragma unroll
    for (int g = 0; g < 4; ++g) {
      int i = 2 * w + j + 8 * g;
      #pragma unroll
      for (int kk = 0; kk < 4; ++kk)
        bregs[j][g][kk] = *(const f16x8*)(WhF + (size_t)(kk * 32 + i) * 512 + lane * 8);
    }
  float bv[2][4];
  #pragma unroll
  for (int j = 0; j < 2; ++j)
    #pragma unroll
    for (int g = 0; g < 4; ++g)
      bv[j][g] = bias[(2 * w + j + 8 * g) * 16 + l16];

  // LN weight slice for this lane (dims kk*32 + quad*8 + 0..7)
  f32x4 lw4[4][2], lb4[4][2];
  #pragma unroll
  for (int kk = 0; kk < 4; ++kk)
    #pragma unroll
    for (int p = 0; p < 2; ++p) {
      int d0 = kk * 32 + quad * 8 + p * 4;
      lw4[kk][p] = *(const f32x4*)(lw + d0);
      lb4[kk][p] = *(const f32x4*)(lb + d0);
    }

  __syncthreads();   // staging complete; abuf read-only from here

  #pragma unroll 1
  for (int t16 = 0; t16 < 8; ++t16) {
    int m0 = m_base + t16 * 16;
    int rloc = t16 * 16 + l16;   // local A-row for this lane

    f32x4 v[4][2];
    #pragma unroll
    for (int kk = 0; kk < 4; ++kk)
      #pragma unroll
      for (int p = 0; p < 2; ++p) {
        int c = kk * 8 + quad * 2 + p;
        int cw = (c & 24) | ((c ^ rloc) & 7);
        v[kk][p] = __builtin_bit_cast(f32x4, abuf[rloc][cw]);
      }
    float s1 = 0.f, s2 = 0.f;
    #pragma unroll
    for (int kk = 0; kk < 4; ++kk)
      #pragma unroll
      for (int p = 0; p < 2; ++p)
        #pragma unroll
        for (int j = 0; j < 4; ++j) {
          float vv = v[kk][p][j];
          s1 += vv; s2 = fmaf(vv, vv, s2);
        }
    s1 += __shfl_xor(s1, 16);  s2 += __shfl_xor(s2, 16);
    s1 += __shfl_xor(s1, 32);  s2 += __shfl_xor(s2, 32);
    float mu = s1 * (1.f / 128.f);
    float var = s2 * (1.f / 128.f) - mu * mu;
    float rs = rsqrtf(var + 1e-5f);

    f16x8 a[4];
    #pragma unroll
    for (int kk = 0; kk < 4; ++kk)
      #pragma unroll
      for (int p = 0; p < 2; ++p)
        #pragma unroll
        for (int j = 0; j < 4; ++j)
          a[kk][p * 4 + j] = (f16)((v[kk][p][j] - mu) * rs * lw4[kk][p][j] + lb4[kk][p][j]);

    f32x4 acc[2][4] = {};
    #pragma unroll
    for (int kk = 0; kk < 4; ++kk)
      #pragma unroll
      for (int j = 0; j < 2; ++j)
        #pragma unroll
        for (int g = 0; g < 4; ++g)
          acc[j][g] = __builtin_amdgcn_mfma_f32_16x16x32_f16(a[kk], bregs[j][g][kk], acc[j][g], 0, 0, 0);

    #pragma unroll
    for (int r = 0; r < 4; ++r) {
      int m = m0 + quad * 4 + r;
      #pragma unroll
      for (int j = 0; j < 2; ++j) {
        uint2 vv;
        vv.x = pk2(acc[j][0][r] + bv[j][0], acc[j][1][r] + bv[j][1]);
        vv.y = pk2(acc[j][2][r] + bv[j][2], acc[j][3][r] + bv[j][3]);
        preP[(size_t)m * Dn + (2 * w + j) * 16 + l16] = vv;
      }
    }
  }
}

// ---------------- fused scan (r4 pipelined schedule, unchanged math) ----------------
// LAST=0 (layer 0): residual x gathered directly from emb[ids[t]] per step;
//                   writes xout = x1.
// LAST=1 (layer 1): residual from x1; mean-pool accumulated in-register; head
//                   MLP (128->64 relu ->2) computed in the epilogue via LDS.
template<int LAST>
__global__ __launch_bounds__(256, 1) void k_scan(const uint2* __restrict__ preP,
                                                 const f16* __restrict__ RT,
                                                 const float* __restrict__ gnw,
                                                 const float* __restrict__ xsrc,
                                                 const int* __restrict__ ids,
                                                 float* __restrict__ xout,
                                                 const float* __restrict__ hw1,
                                                 const float* __restrict__ hb1,
                                                 const float* __restrict__ hw2,
                                                 const float* __restrict__ hb2,
                                                 float* __restrict__ out) {
  const int w = threadIdx.x >> 6;       // wave 0..3
  const int lane = threadIdx.x & 63;
  const int s = w >> 1;                 // seq within block
  const int b = blockIdx.x * 2 + s;
  const int d = ((w & 1) << 6) + lane;  // element 0..127 of this seq
  const int head = d >> 5;
  const int e = d & 31;
  const int half = lane >> 5;

  __shared__ __align__(16) f16 hsh[4][64];   // per-wave h exchange
  __shared__ float pool2[2][128];            // LAST: pooled rows
  __shared__ float hid2[2][64];              // LAST: hidden layer

  uint rr[4][16];
  const uint* RT32 = (const uint*)RT;
  #pragma unroll
  for (int g = 0; g < 4; ++g) {
    const uint* p = RT32 + ((g * 4 + head) * 32 + e) * 16;
    #pragma unroll
    for (int j = 0; j < 16; ++j) rr[g][j] = p[j];
  }
  const float gw = gnw[d];
  const f16* hbase = &hsh[w][half * 32];   // my head-group's 32 h values

  hsh[w][lane] = (f16)0.f;   // wave-local, DS in-order

  const uint2* pp = preP + (size_t)b * Ln * Dn + d;   // + t*Dn
  const float* xp = xsrc + (size_t)b * Ln * Dn + d;   // LAST=1 residual path
  const int*   idr = ids + b * Ln;                    // LAST=0 gather path
  float* xo = xout + (size_t)b * Ln * Dn + d;

  // 4-deep prefetch pipeline (preP overrun stays inside workspace)
  uint2 pb[4]; float xb[4]; int idb[4];
  #pragma unroll
  for (int k = 0; k < 4; ++k) {
    pb[k] = pp[(size_t)k * Dn];
    if (LAST) {
      xb[k] = xp[(size_t)k * Dn];
    } else {
      xb[k] = xsrc[(size_t)idr[k] * Dn + d];
      idb[k] = idr[k + 4];
    }
  }

  // preheader: hu for t=0 (all zeros, but read keeps the pipeline uniform)
  uint hu[16];
  read_hu(hbase, hu);

  float cc = 0.f, nc = 0.f, mc = 0.f, psum = 0.f;
  float hprev = 0.f, xprev = 0.f;
  float u1 = 0.f, u2 = 0.f;   // 16-row partial GN sums of step t-1
  int   w1 = 0,   w2 = 0;     // raw ds_swizzle results (other 16-row sums)

  #pragma unroll 1
  for (int t = 0; t < Ln; t += 4) {
    #pragma unroll
    for (int k = 0; k < 4; ++k) {
      int tt = t + k;
      uint2 pc = pb[k]; float xc = xb[k];
      pb[k] = pp[(size_t)(tt + 4) * Dn];
      if (LAST) {
        xb[k] = xp[(size_t)(tt + 4) * Dn];
      } else {
        xb[k] = xsrc[(size_t)idb[k] * Dn + d];
        int ni = tt + 8;
        idb[k] = idr[ni > 127 ? 127 : ni];
      }

      // GN of step tt-1: combine deferred swizzle halves here
      if (tt > 0) {
        float s1 = u1 + __builtin_bit_cast(float, w1);
        float s2 = u2 + __builtin_bit_cast(float, w2);
        float mu = s1 * (1.f / 32.f);
        float va = s2 * (1.f / 32.f) - mu * mu;
        float ov = xprev + (hprev - mu) * rsqrtf(va + 1e-5f) * gw;
        if (LAST) psum += ov;
        else      xo[(size_t)(tt - 1) * Dn] = ov;
      }

      // recurrence dot products: 8 chains of 8 (2-way split per gate)
      float a0 = 0.f, a1 = 0.f, a2 = 0.f, a3 = 0.f;
      float c0 = 0.f, c1 = 0.f, c2 = 0.f, c3 = 0.f;
      #pragma unroll
      for (int j = 0; j < 8; ++j) {
        a0 = fdot2f(hu[j], rr[0][j], a0);
        a1 = fdot2f(hu[j], rr[1][j], a1);
        a2 = fdot2f(hu[j], rr[2][j], a2);
        a3 = fdot2f(hu[j], rr[3][j], a3);
        c0 = fdot2f(hu[j + 8], rr[0][j + 8], c0);
        c1 = fdot2f(hu[j + 8], rr[1][j + 8], c1);
        c2 = fdot2f(hu[j + 8], rr[2][j + 8], c2);
        c3 = fdot2f(hu[j + 8], rr[3][j + 8], c3);
      }
      f16x2 lo = __builtin_bit_cast(f16x2, pc.x);
      f16x2 hi = __builtin_bit_cast(f16x2, pc.y);
      float it = ((float)lo[0] + a0) + c0;
      float ft = ((float)lo[1] + a1) + c1;
      float zt = ((float)hi[0] + a2) + c2;
      float ot = ((float)hi[1] + a3) + c3;

      float mn = fmaxf(ft + mc, it);
      float iv = __expf(it - mn);
      float fv = __expf(ft + mc - mn);
      float zc = fminf(fmaxf(zt, -15.f), 15.f);
      float ez = __expf(2.f * zc);
      float tz = (ez - 1.f) * __builtin_amdgcn_rcpf(ez + 1.f);
      float cn = fv * cc + iv * tz;
      float nn = fv * nc + iv;
      // h = sigmoid(ot) * c / n = c / ((1 + exp(-ot)) * n)  — single rcp
      float hn = cn * __builtin_amdgcn_rcpf((1.f + __expf(-ot)) * nn);
      cc = cn; nc = nn; mc = mn;

      // --- DS schedule for next step (issue-only, no consumption here) ---
      hsh[w][lane] = (f16)hn;                       // DS op 1: h exchange

      float t1v = hn, t2v = hn * hn;                // VALU rors: 16-row sums
      t1v += rorf<0x121>(t1v);  t2v += rorf<0x121>(t2v);   // ror 1
      t1v += rorf<0x122>(t1v);  t2v += rorf<0x122>(t2v);   // ror 2
      t1v += rorf<0x124>(t1v);  t2v += rorf<0x124>(t2v);   // ror 4
      t1v += rorf<0x128>(t1v);  t2v += rorf<0x128>(t2v);   // ror 8
      w1 = swz16i(t1v);                             // DS ops 2,3: xor-16
      w2 = swz16i(t2v);                             //   (combined next step)
      u1 = t1v; u2 = t2v;

      read_hu(hbase, hu);                           // DS ops 4..7: hu for t+1

      hprev = hn; xprev = xc;
    }
  }

  // epilogue: groupnorm of step 127
  {
    float s1 = u1 + __builtin_bit_cast(float, w1);
    float s2 = u2 + __builtin_bit_cast(float, w2);
    float mu = s1 * (1.f / 32.f);
    float va = s2 * (1.f / 32.f) - mu * mu;
    float ov = xprev + (hprev - mu) * rsqrtf(va + 1e-5f) * gw;
    if (LAST) {
      psum += ov;
      pool2[s][d] = psum * (1.f / 128.f);
      __syncthreads();
      // head MLP: waves 0,2 handle local seqs 0,1
      if ((w & 1) == 0) {
        int sq = w >> 1;
        float acc = hb1[lane];
        const float* wr = hw1 + (size_t)lane * Dn;
        const float* pl = &pool2[sq][0];
        #pragma unroll 8
        for (int dd = 0; dd < Dn; dd += 4) {
          f32x4 wv = *(const f32x4*)(wr + dd);
          acc += wv[0]*pl[dd] + wv[1]*pl[dd+1] + wv[2]*pl[dd+2] + wv[3]*pl[dd+3];
        }
        hid2[sq][lane] = fmaxf(acc, 0.f);
      }
      __syncthreads();
      if ((w & 1) == 0 && lane < 2) {
        int sq = w >> 1;
        float acc = hb2[lane];
        const float* wr = hw2 + lane * 64;
        #pragma unroll 4
        for (int j = 0; j < 64; ++j) acc += hid2[sq][j] * wr[j];
        out[(blockIdx.x * 2 + sq) * 2 + lane] = acc;
      }
    } else {
      xo[(size_t)(Ln - 1) * Dn] = ov;
    }
  }
}

extern "C" void kernel_launch(void* const* d_in, const int* in_sizes, int n_in,
                              void* d_out, int out_size, void* d_ws, size_t ws_size,
                              hipStream_t stream) {
  const int*   ids  = (const int*)d_in[0];
  const float* emb  = (const float*)d_in[1];
  const float* ln_w = (const float*)d_in[2];
  const float* ln_b = (const float*)d_in[3];
  const float* Wg   = (const float*)d_in[4];
  const float* Rg   = (const float*)d_in[5];
  const float* bg   = (const float*)d_in[6];
  const float* gn_w = (const float*)d_in[7];
  const float* w1   = (const float*)d_in[8];
  const float* b1   = (const float*)d_in[9];
  const float* w2   = (const float*)d_in[10];
  const float* b2   = (const float*)d_in[11];
  float* out = (float*)d_out;

  char* ws = (char*)d_ws;
  uint2* preP = (uint2*)ws;                        // 67,108,864 B
  float* x1   = (float*)(ws + 67108864);           // 33,554,432 B
  f16*   WhF  = (f16*)(ws + 100663296);            //    262,144 B
  f16*   RT   = (f16*)(ws + 100663296 + 262144);   //     65,536 B

  k_convert<<<192, 256, 0, stream>>>(Wg, Rg, WhF, RT);

  // layer 0: gather+LN fused into GEMM; scan gathers residual from emb directly
  k_gemm<1><<<512, 256, 0, stream>>>(emb, ids, ln_w, ln_b, WhF, bg, preP);
  k_scan<0><<<256, 256, 0, stream>>>(preP, RT, gn_w, emb, ids, x1,
                                     nullptr, nullptr, nullptr, nullptr, nullptr);
  // layer 1: LN fused into GEMM; head MLP fused into scan epilogue
  k_gemm<0><<<512, 256, 0, stream>>>(x1, nullptr, ln_w + Dn, ln_b + Dn,
                                     WhF + 65536, bg + Cn, preP);
  k_scan<1><<<256, 256, 0, stream>>>(preP, RT + 16384, gn_w + Dn, x1, nullptr,
                                     nullptr, w1, b1, w2, b2, out);
}

// Round 17
// 219.348 us; speedup vs baseline: 2.5691x; 1.0031x over previous
//
#include <hip/hip_runtime.h>

typedef _Float16 f16;
typedef unsigned int uint;
typedef f16 f16x2 __attribute__((ext_vector_type(2)));
typedef f16 f16x8 __attribute__((ext_vector_type(8)));
typedef __fp16 h16x2 __attribute__((ext_vector_type(2)));
typedef float f32x4 __attribute__((ext_vector_type(4)));

#define Bn 512
#define Ln 128
#define Dn 128
#define Cn 512   // 4 gates * D

__device__ __forceinline__ float fdot2f(uint a, uint b, float c) {
#if __has_builtin(__builtin_amdgcn_fdot2)
  return __builtin_amdgcn_fdot2(__builtin_bit_cast(f16x2, a),
                                __builtin_bit_cast(f16x2, b), c, false);
#else
  f16x2 av = __builtin_bit_cast(f16x2, a), bv = __builtin_bit_cast(f16x2, b);
  return c + (float)av[0] * (float)bv[0] + (float)av[1] * (float)bv[1];
#endif
}

__device__ __forceinline__ uint pk2(float a, float b) {
#if __has_builtin(__builtin_amdgcn_cvt_pkrtz)
  h16x2 v = __builtin_amdgcn_cvt_pkrtz(a, b);
  return __builtin_bit_cast(uint, v);
#else
  f16x2 v; v[0] = (f16)a; v[1] = (f16)b;
  return __builtin_bit_cast(uint, v);
#endif
}

// DPP row_ror<N> (VALU, 2-cyc): rotational reduce within 16-lane rows.
template<int CTRL>
__device__ __forceinline__ float rorf(float x) {
#if __has_builtin(__builtin_amdgcn_mov_dpp)
  int r = __builtin_amdgcn_mov_dpp(__builtin_bit_cast(int, x), CTRL, 0xF, 0xF, true);
  return __builtin_bit_cast(float, r);
#else
  return __shfl_xor(x, (CTRL - 0x120));
#endif
}

// lane ^ 16 exchange via ds_swizzle (BitMode xor=16, and=0x1F) — LDS pipe,
// result intentionally NOT consumed at issue site (deferred to next step).
__device__ __forceinline__ int swz16i(float x) {
#if __has_builtin(__builtin_amdgcn_ds_swizzle)
  return __builtin_amdgcn_ds_swizzle(__builtin_bit_cast(int, x), 0x401F);
#else
  return __builtin_bit_cast(int, __shfl_xor(x, 16));
#endif
}

__device__ __forceinline__ void read_hu(const f16* base, uint hu[16]) {
  const uint4* hq = (const uint4*)base;
  uint4 q0 = hq[0], q1 = hq[1], q2 = hq[2], q3 = hq[3];
  hu[0]=q0.x; hu[1]=q0.y; hu[2]=q0.z; hu[3]=q0.w;
  hu[4]=q1.x; hu[5]=q1.y; hu[6]=q1.z; hu[7]=q1.w;
  hu[8]=q2.x; hu[9]=q2.y; hu[10]=q2.z; hu[11]=q2.w;
  hu[12]=q3.x; hu[13]=q3.y; hu[14]=q3.z; hu[15]=q3.w;
}

// ---------------- convert: W -> MFMA-fragment-ordered f16 (WhF), R -> transposed f16 ----------------
__global__ __launch_bounds__(256) void k_convert(const float* __restrict__ Wg,
                                                 const float* __restrict__ Rg,
                                                 f16* __restrict__ WhF,
                                                 f16* __restrict__ RT) {
  int i = blockIdx.x * 256 + threadIdx.x;
  const int nWfrag = 2 * 4 * 32 * 64;   // 16384 groups of 8 f16
  if (i < nWfrag) {
    int lane = i & 63;
    int ii   = (i >> 6) & 31;
    int kk   = (i >> 11) & 3;
    int l    = i >> 13;
    int c = ii * 16 + (lane & 15);
    int d = kk * 32 + ((lane >> 4) << 3);
    const float* src = Wg + ((size_t)(l * 512 + c) * 128 + d);
    f16* dst = WhF + (size_t)i * 8;
    #pragma unroll
    for (int j = 0; j < 8; ++j) dst[j] = (f16)src[j];
  } else {
    int j = i - nWfrag;  // 32768 = 2*4*4*32*32
    if (j < 32768) {
      int dd = j & 31;
      int e  = (j >> 5) & 31;
      int hh = (j >> 10) & 3;
      int g  = (j >> 12) & 3;
      int l  = j >> 14;
      RT[j] = (f16)Rg[((((l * 4 + g) * 4 + hh) * 32 + dd) * 32) + e];
    }
  }
}

// ---------------- GEMM: B-resident registers, FULL-depth LDS A-stage ----------------
// r6 compute structure with all 128 A-rows staged to LDS up front — 16
// dwordx4 loads/thread issued back-to-back (ONE exposed gather latency per
// block instead of 8 serialized per-tile latencies). Plain ds_write staging
// (no global_load_lds — r11's race) and no persistent register state
// (staging regs die before bregs load — r9's spill lesson). XOR col-swizzle
// (both sides) spreads the LN read pattern across banks.
// [Session-verified best: 220.0 µs total, r15.]
template<int EMB>
__global__ __launch_bounds__(256, 2) void k_gemm(const float* __restrict__ xsrc,
                                                 const int* __restrict__ ids,
                                                 const float* __restrict__ lw,
                                                 const float* __restrict__ lb,
                                                 const f16* __restrict__ WhF,
                                                 const float* __restrict__ bias,
                                                 uint2* __restrict__ preP) {
  int tid = threadIdx.x;
  int w = tid >> 6;
  int lane = tid & 63;
  int l16 = lane & 15, quad = lane >> 4;
  int m_base = blockIdx.x * 128;

  __shared__ __align__(16) uint4 abuf[128][32];   // 64 KB: 128 rows x 32 16B-segs

  // ---- stage all 128 rows: issue all 16 gathers, then write swizzled ----
  {
    uint4 stg[16];
    #pragma unroll
    for (int s = 0; s < 16; ++s) {
      int seg = s * 256 + tid;
      int row = seg >> 5, col = seg & 31;
      const float* gp;
      if (EMB) gp = xsrc + (size_t)ids[m_base + row] * Dn + col * 4;
      else     gp = xsrc + (size_t)(m_base + row) * Dn + col * 4;
      stg[s] = *(const uint4*)gp;
    }
    #pragma unroll
    for (int s = 0; s < 16; ++s) {
      int seg = s * 256 + tid;
      int row = seg >> 5, col = seg & 31;
      int colw = (col & 24) | ((col ^ row) & 7);
      abuf[row][colw] = stg[s];
    }
  }

  // resident B fragments: [j][g][kk], i = 2w + j + 8g
  f16x8 bregs[2][4][4];
  #pragma unroll
  for (int j = 0; j < 2; ++j)
    #pragma unroll
    for (int g = 0; g < 4; ++g) {
      int i = 2 * w + j + 8 * g;
      #pragma unroll
      for (int kk = 0; kk < 4; ++kk)
        bregs[j][g][kk] = *(const f16x8*)(WhF + (size_t)(kk * 32 + i) * 512 + lane * 8);
    }
  float bv[2][4];
  #pragma unroll
  for (int j = 0; j < 2; ++j)
    #pragma unroll
    for (int g = 0; g < 4; ++g)
      bv[j][g] = bias[(2 * w + j + 8 * g) * 16 + l16];

  // LN weight slice for this lane (dims kk*32 + quad*8 + 0..7)
  f32x4 lw4[4][2], lb4[4][2];
  #pragma unroll
  for (int kk = 0; kk < 4; ++kk)
    #pragma unroll
    for (int p = 0; p < 2; ++p) {
      int d0 = kk * 32 + quad * 8 + p * 4;
      lw4[kk][p] = *(const f32x4*)(lw + d0);
      lb4[kk][p] = *(const f32x4*)(lb + d0);
    }

  __syncthreads();   // staging complete; abuf read-only from here

  #pragma unroll 1
  for (int t16 = 0; t16 < 8; ++t16) {
    int m0 = m_base + t16 * 16;
    int rloc = t16 * 16 + l16;   // local A-row for this lane

    f32x4 v[4][2];
    #pragma unroll
    for (int kk = 0; kk < 4; ++kk)
      #pragma unroll
      for (int p = 0; p < 2; ++p) {
        int c = kk * 8 + quad * 2 + p;
        int cw = (c & 24) | ((c ^ rloc) & 7);
        v[kk][p] = __builtin_bit_cast(f32x4, abuf[rloc][cw]);
      }
    float s1 = 0.f, s2 = 0.f;
    #pragma unroll
    for (int kk = 0; kk < 4; ++kk)
      #pragma unroll
      for (int p = 0; p < 2; ++p)
        #pragma unroll
        for (int j = 0; j < 4; ++j) {
          float vv = v[kk][p][j];
          s1 += vv; s2 = fmaf(vv, vv, s2);
        }
    s1 += __shfl_xor(s1, 16);  s2 += __shfl_xor(s2, 16);
    s1 += __shfl_xor(s1, 32);  s2 += __shfl_xor(s2, 32);
    float mu = s1 * (1.f / 128.f);
    float var = s2 * (1.f / 128.f) - mu * mu;
    float rs = rsqrtf(var + 1e-5f);

    f16x8 a[4];
    #pragma unroll
    for (int kk = 0; kk < 4; ++kk)
      #pragma unroll
      for (int p = 0; p < 2; ++p)
        #pragma unroll
        for (int j = 0; j < 4; ++j)
          a[kk][p * 4 + j] = (f16)((v[kk][p][j] - mu) * rs * lw4[kk][p][j] + lb4[kk][p][j]);

    f32x4 acc[2][4] = {};
    #pragma unroll
    for (int kk = 0; kk < 4; ++kk)
      #pragma unroll
      for (int j = 0; j < 2; ++j)
        #pragma unroll
        for (int g = 0; g < 4; ++g)
          acc[j][g] = __builtin_amdgcn_mfma_f32_16x16x32_f16(a[kk], bregs[j][g][kk], acc[j][g], 0, 0, 0);

    #pragma unroll
    for (int r = 0; r < 4; ++r) {
      int m = m0 + quad * 4 + r;
      #pragma unroll
      for (int j = 0; j < 2; ++j) {
        uint2 vv;
        vv.x = pk2(acc[j][0][r] + bv[j][0], acc[j][1][r] + bv[j][1]);
        vv.y = pk2(acc[j][2][r] + bv[j][2], acc[j][3][r] + bv[j][3]);
        preP[(size_t)m * Dn + (2 * w + j) * 16 + l16] = vv;
      }
    }
  }
}

// ---------------- fused scan (r4 pipelined schedule, unchanged math) ----------------
// LAST=0 (layer 0): residual x gathered directly from emb[ids[t]] per step;
//                   writes xout = x1.
// LAST=1 (layer 1): residual from x1; mean-pool accumulated in-register; head
//                   MLP (128->64 relu ->2) computed in the epilogue via LDS.
template<int LAST>
__global__ __launch_bounds__(256, 1) void k_scan(const uint2* __restrict__ preP,
                                                 const f16* __restrict__ RT,
                                                 const float* __restrict__ gnw,
                                                 const float* __restrict__ xsrc,
                                                 const int* __restrict__ ids,
                                                 float* __restrict__ xout,
                                                 const float* __restrict__ hw1,
                                                 const float* __restrict__ hb1,
                                                 const float* __restrict__ hw2,
                                                 const float* __restrict__ hb2,
                                                 float* __restrict__ out) {
  const int w = threadIdx.x >> 6;       // wave 0..3
  const int lane = threadIdx.x & 63;
  const int s = w >> 1;                 // seq within block
  const int b = blockIdx.x * 2 + s;
  const int d = ((w & 1) << 6) + lane;  // element 0..127 of this seq
  const int head = d >> 5;
  const int e = d & 31;
  const int half = lane >> 5;

  __shared__ __align__(16) f16 hsh[4][64];   // per-wave h exchange
  __shared__ float pool2[2][128];            // LAST: pooled rows
  __shared__ float hid2[2][64];              // LAST: hidden layer

  uint rr[4][16];
  const uint* RT32 = (const uint*)RT;
  #pragma unroll
  for (int g = 0; g < 4; ++g) {
    const uint* p = RT32 + ((g * 4 + head) * 32 + e) * 16;
    #pragma unroll
    for (int j = 0; j < 16; ++j) rr[g][j] = p[j];
  }
  const float gw = gnw[d];
  const f16* hbase = &hsh[w][half * 32];   // my head-group's 32 h values

  hsh[w][lane] = (f16)0.f;   // wave-local, DS in-order

  const uint2* pp = preP + (size_t)b * Ln * Dn + d;   // + t*Dn
  const float* xp = xsrc + (size_t)b * Ln * Dn + d;   // LAST=1 residual path
  const int*   idr = ids + b * Ln;                    // LAST=0 gather path
  float* xo = xout + (size_t)b * Ln * Dn + d;

  // 4-deep prefetch pipeline (preP overrun stays inside workspace)
  uint2 pb[4]; float xb[4]; int idb[4];
  #pragma unroll
  for (int k = 0; k < 4; ++k) {
    pb[k] = pp[(size_t)k * Dn];
    if (LAST) {
      xb[k] = xp[(size_t)k * Dn];
    } else {
      xb[k] = xsrc[(size_t)idr[k] * Dn + d];
      idb[k] = idr[k + 4];
    }
  }

  // preheader: hu for t=0 (all zeros, but read keeps the pipeline uniform)
  uint hu[16];
  read_hu(hbase, hu);

  float cc = 0.f, nc = 0.f, mc = 0.f, psum = 0.f;
  float hprev = 0.f, xprev = 0.f;
  float u1 = 0.f, u2 = 0.f;   // 16-row partial GN sums of step t-1
  int   w1 = 0,   w2 = 0;     // raw ds_swizzle results (other 16-row sums)

  #pragma unroll 1
  for (int t = 0; t < Ln; t += 4) {
    #pragma unroll
    for (int k = 0; k < 4; ++k) {
      int tt = t + k;
      uint2 pc = pb[k]; float xc = xb[k];
      pb[k] = pp[(size_t)(tt + 4) * Dn];
      if (LAST) {
        xb[k] = xp[(size_t)(tt + 4) * Dn];
      } else {
        xb[k] = xsrc[(size_t)idb[k] * Dn + d];
        int ni = tt + 8;
        idb[k] = idr[ni > 127 ? 127 : ni];
      }

      // GN of step tt-1: combine deferred swizzle halves here
      if (tt > 0) {
        float s1 = u1 + __builtin_bit_cast(float, w1);
        float s2 = u2 + __builtin_bit_cast(float, w2);
        float mu = s1 * (1.f / 32.f);
        float va = s2 * (1.f / 32.f) - mu * mu;
        float ov = xprev + (hprev - mu) * rsqrtf(va + 1e-5f) * gw;
        if (LAST) psum += ov;
        else      xo[(size_t)(tt - 1) * Dn] = ov;
      }

      // recurrence dot products: 8 chains of 8 (2-way split per gate)
      float a0 = 0.f, a1 = 0.f, a2 = 0.f, a3 = 0.f;
      float c0 = 0.f, c1 = 0.f, c2 = 0.f, c3 = 0.f;
      #pragma unroll
      for (int j = 0; j < 8; ++j) {
        a0 = fdot2f(hu[j], rr[0][j], a0);
        a1 = fdot2f(hu[j], rr[1][j], a1);
        a2 = fdot2f(hu[j], rr[2][j], a2);
        a3 = fdot2f(hu[j], rr[3][j], a3);
        c0 = fdot2f(hu[j + 8], rr[0][j + 8], c0);
        c1 = fdot2f(hu[j + 8], rr[1][j + 8], c1);
        c2 = fdot2f(hu[j + 8], rr[2][j + 8], c2);
        c3 = fdot2f(hu[j + 8], rr[3][j + 8], c3);
      }
      f16x2 lo = __builtin_bit_cast(f16x2, pc.x);
      f16x2 hi = __builtin_bit_cast(f16x2, pc.y);
      float it = ((float)lo[0] + a0) + c0;
      float ft = ((float)lo[1] + a1) + c1;
      float zt = ((float)hi[0] + a2) + c2;
      float ot = ((float)hi[1] + a3) + c3;

      float mn = fmaxf(ft + mc, it);
      float iv = __expf(it - mn);
      float fv = __expf(ft + mc - mn);
      float zc = fminf(fmaxf(zt, -15.f), 15.f);
      float ez = __expf(2.f * zc);
      float tz = (ez - 1.f) * __builtin_amdgcn_rcpf(ez + 1.f);
      float cn = fv * cc + iv * tz;
      float nn = fv * nc + iv;
      // h = sigmoid(ot) * c / n = c / ((1 + exp(-ot)) * n)  — single rcp
      float hn = cn * __builtin_amdgcn_rcpf((1.f + __expf(-ot)) * nn);
      cc = cn; nc = nn; mc = mn;

      // --- DS schedule for next step (issue-only, no consumption here) ---
      hsh[w][lane] = (f16)hn;                       // DS op 1: h exchange

      float t1v = hn, t2v = hn * hn;                // VALU rors: 16-row sums
      t1v += rorf<0x121>(t1v);  t2v += rorf<0x121>(t2v);   // ror 1
      t1v += rorf<0x122>(t1v);  t2v += rorf<0x122>(t2v);   // ror 2
      t1v += rorf<0x124>(t1v);  t2v += rorf<0x124>(t2v);   // ror 4
      t1v += rorf<0x128>(t1v);  t2v += rorf<0x128>(t2v);   // ror 8
      w1 = swz16i(t1v);                             // DS ops 2,3: xor-16
      w2 = swz16i(t2v);                             //   (combined next step)
      u1 = t1v; u2 = t2v;

      read_hu(hbase, hu);                           // DS ops 4..7: hu for t+1

      hprev = hn; xprev = xc;
    }
  }

  // epilogue: groupnorm of step 127
  {
    float s1 = u1 + __builtin_bit_cast(float, w1);
    float s2 = u2 + __builtin_bit_cast(float, w2);
    float mu = s1 * (1.f / 32.f);
    float va = s2 * (1.f / 32.f) - mu * mu;
    float ov = xprev + (hprev - mu) * rsqrtf(va + 1e-5f) * gw;
    if (LAST) {
      psum += ov;
      pool2[s][d] = psum * (1.f / 128.f);
      __syncthreads();
      // head MLP: waves 0,2 handle local seqs 0,1
      if ((w & 1) == 0) {
        int sq = w >> 1;
        float acc = hb1[lane];
        const float* wr = hw1 + (size_t)lane * Dn;
        const float* pl = &pool2[sq][0];
        #pragma unroll 8
        for (int dd = 0; dd < Dn; dd += 4) {
          f32x4 wv = *(const f32x4*)(wr + dd);
          acc += wv[0]*pl[dd] + wv[1]*pl[dd+1] + wv[2]*pl[dd+2] + wv[3]*pl[dd+3];
        }
        hid2[sq][lane] = fmaxf(acc, 0.f);
      }
      __syncthreads();
      if ((w & 1) == 0 && lane < 2) {
        int sq = w >> 1;
        float acc = hb2[lane];
        const float* wr = hw2 + lane * 64;
        #pragma unroll 4
        for (int j = 0; j < 64; ++j) acc += hid2[sq][j] * wr[j];
        out[(blockIdx.x * 2 + sq) * 2 + lane] = acc;
      }
    } else {
      xo[(size_t)(Ln - 1) * Dn] = ov;
    }
  }
}

extern "C" void kernel_launch(void* const* d_in, const int* in_sizes, int n_in,
                              void* d_out, int out_size, void* d_ws, size_t ws_size,
                              hipStream_t stream) {
  const int*   ids  = (const int*)d_in[0];
  const float* emb  = (const float*)d_in[1];
  const float* ln_w = (const float*)d_in[2];
  const float* ln_b = (const float*)d_in[3];
  const float* Wg   = (const float*)d_in[4];
  const float* Rg   = (const float*)d_in[5];
  const float* bg   = (const float*)d_in[6];
  const float* gn_w = (const float*)d_in[7];
  const float* w1   = (const float*)d_in[8];
  const float* b1   = (const float*)d_in[9];
  const float* w2   = (const float*)d_in[10];
  const float* b2   = (const float*)d_in[11];
  float* out = (float*)d_out;

  char* ws = (char*)d_ws;
  uint2* preP = (uint2*)ws;                        // 67,108,864 B
  float* x1   = (float*)(ws + 67108864);           // 33,554,432 B
  f16*   WhF  = (f16*)(ws + 100663296);            //    262,144 B
  f16*   RT   = (f16*)(ws + 100663296 + 262144);   //     65,536 B

  k_convert<<<192, 256, 0, stream>>>(Wg, Rg, WhF, RT);

  // layer 0: gather+LN fused into GEMM; scan gathers residual from emb directly
  k_gemm<1><<<512, 256, 0, stream>>>(emb, ids, ln_w, ln_b, WhF, bg, preP);
  k_scan<0><<<256, 256, 0, stream>>>(preP, RT, gn_w, emb, ids, x1,
                                     nullptr, nullptr, nullptr, nullptr, nullptr);
  // layer 1: LN fused into GEMM; head MLP fused into scan epilogue
  k_gemm<0><<<512, 256, 0, stream>>>(x1, nullptr, ln_w + Dn, ln_b + Dn,
                                     WhF + 65536, bg + Cn, preP);
  k_scan<1><<<256, 256, 0, stream>>>(preP, RT + 16384, gn_w + Dn, x1, nullptr,
                                     nullptr, w1, b1, w2, b2, out);
}